// Round 4
// baseline (992.862 us; speedup 1.0000x reference)
//
#include <hip/hip_runtime.h>
#include <hip/hip_bf16.h>

#define NL 3
#define HD 64

typedef unsigned char u8;

__device__ __forceinline__ float sigf(float x){ return 1.f/(1.f+__expf(-x)); }

__device__ __forceinline__ float wsum(float v){
  #pragma unroll
  for (int off=32; off; off>>=1) v += __shfl_xor(v, off, 64);
  return v;
}

// dtype-flexible load: bf==1 -> bf16, bf==0 -> f32
__device__ __forceinline__ float ldin(const void* p, size_t i, int bf){
  return bf ? __bfloat162float(((const __hip_bfloat16*)p)[i]) : ((const float*)p)[i];
}

// -------- runtime dtype probe: bf16 halves of N(0,0.05) data have sane exponents --------
__global__ void k_dtype(const unsigned short* __restrict__ probe, int* __restrict__ flag){
  int lane = threadIdx.x & 63;
  unsigned short h = probe[lane];
  int e = (h >> 7) & 0xFF;
  int sane = ((h & 0x7FFF) == 0) || (e >= 96 && e <= 132);
  unsigned long long m = __ballot(sane != 0);
  if (lane == 0) flag[0] = (__popcll(m) >= 56) ? 1 : 0;
}

// -------- convert/transpose all weights into f32 scratch --------
__global__ void k_prep(
    const void* __restrict__ W_h, const void* __restrict__ Ws,
    const void* __restrict__ Wih, const void* __restrict__ Whh,
    const void* __restrict__ bih, const void* __restrict__ bhh,
    const void* __restrict__ wal, const void* __restrict__ bal,
    const void* __restrict__ Wf,  const void* __restrict__ rel,
    float* __restrict__ WhT, float* __restrict__ WsT,
    float* __restrict__ WihF, float* __restrict__ WhhF,
    float* __restrict__ biF, float* __restrict__ bhF,
    float* __restrict__ waF, float* __restrict__ baF,
    float* __restrict__ WfF, float* __restrict__ REL,
    const int* __restrict__ flag, int NR)
{
  int bf = flag[0];
  int j = blockIdx.x*256 + threadIdx.x;
  const int sWT = NL*HD*HD, sWI = NL*192*HD, sB = NL*192;
  if (j < sWT){ int l=j/(HD*HD), q=j%(HD*HD), a=q/HD, h=q%HD; WhT[j]=ldin(W_h,(size_t)(l*HD+h)*HD+a,bf); return; } j-=sWT;
  if (j < sWT){ int l=j/(HD*HD), q=j%(HD*HD), a=q/HD, h=q%HD; WsT[j]=ldin(Ws ,(size_t)(l*HD+h)*HD+a,bf); return; } j-=sWT;
  if (j < sWI){ WihF[j]=ldin(Wih,j,bf); return; } j-=sWI;
  if (j < sWI){ WhhF[j]=ldin(Whh,j,bf); return; } j-=sWI;
  if (j < sB){ biF[j]=ldin(bih,j,bf); return; } j-=sB;
  if (j < sB){ bhF[j]=ldin(bhh,j,bf); return; } j-=sB;
  if (j < NL*HD){ waF[j]=ldin(wal,j,bf); return; } j-=NL*HD;
  if (j < NL){ baF[j]=ldin(bal,j,bf); return; } j-=NL;
  if (j < HD){ WfF[j]=ldin(Wf,j,bf); return; } j-=HD;
  if (j < NL*NR*HD){ REL[j]=ldin(rel,j,bf); return; }
}

// -------- per-(layer,rel) hr@Wr and per-(layer,batch) h_qr@Wqr+bqr tables --------
__global__ void k_tables(
    const void* __restrict__ rel, const void* __restrict__ Wr,
    const void* __restrict__ Wqr, const void* __restrict__ bqr,
    const int* __restrict__ q_rel,
    float* __restrict__ R2, float* __restrict__ QR,
    const int* __restrict__ flag, int NR, int B)
{
  int bf = flag[0];
  int lane = threadIdx.x & 63;
  int bid = blockIdx.x;
  if (bid < NL*NR){
    int l = bid/NR, r = bid%NR;
    float x = ldin(rel,(size_t)(l*NR+r)*HD + lane,bf);
    float acc = 0.f;
    #pragma unroll
    for (int h=0; h<HD; ++h)
      acc = fmaf(__shfl(x, h, 64), ldin(Wr,(size_t)(l*HD+h)*HD + lane,bf), acc);
    R2[(size_t)bid*HD + lane] = acc;
  } else {
    int b2 = bid - NL*NR;
    int l = b2/B, b = b2%B;
    int r = q_rel[b];
    float x = ldin(rel,(size_t)(l*NR+r)*HD + lane,bf);
    float acc = ldin(bqr,(size_t)l*HD + lane,bf);
    #pragma unroll
    for (int h=0; h<HD; ++h)
      acc = fmaf(__shfl(x, h, 64), ldin(Wqr,(size_t)(l*HD+h)*HD + lane,bf), acc);
    QR[(size_t)b2*HD + lane] = acc;
  }
}

// -------- seed query nodes; build initial live list; HS2 = hid @ Ws[0] --------
__global__ void k_init(
    const int* __restrict__ qsub, const int* __restrict__ q_rel,
    const void* __restrict__ qre, const float* __restrict__ WsT0,
    float* __restrict__ hid, float* __restrict__ HS2, u8* __restrict__ liveB,
    int* __restrict__ stamp, int* __restrict__ plist, int* __restrict__ pcnt,
    const int* __restrict__ flag, int B)
{
  int bf = flag[0];
  int lane = threadIdx.x & 63;
  const float* __restrict__ wsr = WsT0 + (size_t)lane*HD;
  int pc = 0;
  for (int b=0; b<B; ++b){
    int n = qsub[b];
    int r = q_rel[b];
    float v = ldin(qre,(size_t)r*HD + lane,bf);
    hid[(size_t)n*HD + lane] = v;               // last write wins (np .at[].set)
    float acc = 0.f;
    #pragma unroll
    for (int h=0; h<HD; h+=4){
      float4 w = *(const float4*)(wsr + h);
      acc = fmaf(__shfl(v,h  ,64), w.x, acc);
      acc = fmaf(__shfl(v,h+1,64), w.y, acc);
      acc = fmaf(__shfl(v,h+2,64), w.z, acc);
      acc = fmaf(__shfl(v,h+3,64), w.w, acc);
    }
    HS2[(size_t)n*HD + lane] = acc;
    if (lane==0){
      liveB[n] = 1;
      if (stamp[n] != 1){ stamp[n] = 1; plist[pc++] = n; }
    }
  }
  if (lane==0) pcnt[0] = pc;
}

// -------- compact live-edge list --------
__global__ void k_filter(const int* __restrict__ sub, const u8* __restrict__ liveB,
                         int* __restrict__ elist, int* __restrict__ cnt, int E)
{
  int e = blockIdx.x*256 + threadIdx.x;
  if (e >= E) return;
  if (liveB[sub[e]]){
    int i = atomicAdd(cnt, 1);
    elist[i] = e;
  }
}

// -------- edge phase over live edges; mark+append touched obj nodes --------
__global__ void __launch_bounds__(256) k_edge(
    const int* __restrict__ elist, const int* __restrict__ cnt,
    const int* __restrict__ sub, const int* __restrict__ rel_i,
    const int* __restrict__ obj, const int* __restrict__ eb,
    const float* __restrict__ hid, const float* __restrict__ HS2,
    const float* __restrict__ R2l, const float* __restrict__ QRl,
    const float* __restrict__ RELl, const float* __restrict__ waFl,
    const float* __restrict__ baFl, float* __restrict__ agg,
    int* __restrict__ stamp, int* __restrict__ tlist, int* __restrict__ tcnt,
    int ep, int E)
{
  int nlive = cnt[0]; if (nlive > E) nlive = E;
  int lane = threadIdx.x & 63;
  int wid = (blockIdx.x*256 + threadIdx.x) >> 6;
  int nw = gridDim.x*4;
  float wa = waFl[lane];
  float ba = baFl[0];
  for (int i = wid; i < nlive; i += nw){
    int e = elist[i];
    int s = sub[e], r = rel_i[e], o = obj[e], b = eb[e];
    float hs  = hid[(size_t)s*HD + lane];
    float pre = HS2[(size_t)s*HD + lane] + R2l[(size_t)r*HD + lane] + QRl[(size_t)b*HD + lane];
    pre = fmaxf(pre, 0.f);
    float d = wsum(pre*wa) + ba;
    float alpha = sigf(d);
    float msg = alpha * hs * RELl[(size_t)r*HD + lane];
    unsafeAtomicAdd(&agg[(size_t)o*HD + lane], msg);
    if (lane==0){
      int old = atomicExch(&stamp[o], ep);
      if (old != ep){ int idx = atomicAdd(tcnt, 1); tlist[idx] = o; }
    }
  }
}

// -------- node phase over TOUCHED nodes only; epilogue computes next HS2 --------
__global__ void __launch_bounds__(256) k_node(
    const int* __restrict__ tlist, const int* __restrict__ tcnt,
    float* __restrict__ agg, float* __restrict__ hid, float* __restrict__ HS2,
    u8* __restrict__ liveB,
    const float* __restrict__ WhTl, const float* __restrict__ WihFl,
    const float* __restrict__ WhhFl, const float* __restrict__ biFl,
    const float* __restrict__ bhFl, const float* __restrict__ WsTn,
    const float* __restrict__ WfF,
    float* __restrict__ out, int N, int isFirst, int isLast)
{
  int cntv = tcnt[0]; if (cntv > N) cntv = N;
  int lane = threadIdx.x & 63;
  int wid = (blockIdx.x*256 + threadIdx.x) >> 6;
  int nw = gridDim.x*4;
  float bi0=biFl[lane], bi1=biFl[HD+lane], bi2=biFl[2*HD+lane];
  float bh0=bhFl[lane], bh1=bhFl[HD+lane], bh2=bhFl[2*HD+lane];
  float wfv = isLast ? WfF[lane] : 0.f;
  const float* __restrict__ wrow = WhTl + (size_t)lane*HD;
  const float* __restrict__ wi0 = WihFl + (size_t)lane*HD;
  const float* __restrict__ wi1 = WihFl + (size_t)(HD+lane)*HD;
  const float* __restrict__ wi2 = WihFl + (size_t)(2*HD+lane)*HD;
  const float* __restrict__ wh0 = WhhFl + (size_t)lane*HD;
  const float* __restrict__ wh1 = WhhFl + (size_t)(HD+lane)*HD;
  const float* __restrict__ wh2 = WhhFl + (size_t)(2*HD+lane)*HD;
  const float* __restrict__ wsr = WsTn + (size_t)lane*HD;

  for (int i = wid; i < cntv; i += nw){
    int n = tlist[i];
    size_t base = (size_t)n*HD;
    float av = agg[base+lane];
    agg[base+lane] = 0.f;             // restore zeros for next layer's atomics

    // h_mid = relu(agg @ W_h)
    float hm = 0.f;
    #pragma unroll
    for (int h=0; h<HD; h+=4){
      float4 w = *(const float4*)(wrow + h);
      hm = fmaf(__shfl(av,h  ,64), w.x, hm);
      hm = fmaf(__shfl(av,h+1,64), w.y, hm);
      hm = fmaf(__shfl(av,h+2,64), w.z, hm);
      hm = fmaf(__shfl(av,h+3,64), w.w, hm);
    }
    hm = fmaxf(hm, 0.f);
    float mask = (__ballot(hm != 0.f) != 0ull) ? 1.f : 0.f;
    bool wasLive = !isFirst && (liveB[n] != 0);
    float h0v = wasLive ? hid[base+lane] : 0.f;

    float gi0=bi0, gi1=bi1, gi2=bi2;
    float gh0=bh0, gh1=bh1, gh2=bh2;
    #pragma unroll
    for (int h=0; h<HD; h+=4){
      float x0=__shfl(hm,h,64), x1=__shfl(hm,h+1,64), x2=__shfl(hm,h+2,64), x3=__shfl(hm,h+3,64);
      float4 a0 = *(const float4*)(wi0+h);
      float4 a1 = *(const float4*)(wi1+h);
      float4 a2 = *(const float4*)(wi2+h);
      gi0 = fmaf(x0,a0.x,fmaf(x1,a0.y,fmaf(x2,a0.z,fmaf(x3,a0.w,gi0))));
      gi1 = fmaf(x0,a1.x,fmaf(x1,a1.y,fmaf(x2,a1.z,fmaf(x3,a1.w,gi1))));
      gi2 = fmaf(x0,a2.x,fmaf(x1,a2.y,fmaf(x2,a2.z,fmaf(x3,a2.w,gi2))));
    }
    if (wasLive){
      #pragma unroll
      for (int h=0; h<HD; h+=4){
        float y0=__shfl(h0v,h,64), y1=__shfl(h0v,h+1,64), y2=__shfl(h0v,h+2,64), y3=__shfl(h0v,h+3,64);
        float4 b0 = *(const float4*)(wh0+h);
        float4 b1 = *(const float4*)(wh1+h);
        float4 b2 = *(const float4*)(wh2+h);
        gh0 = fmaf(y0,b0.x,fmaf(y1,b0.y,fmaf(y2,b0.z,fmaf(y3,b0.w,gh0))));
        gh1 = fmaf(y0,b1.x,fmaf(y1,b1.y,fmaf(y2,b1.z,fmaf(y3,b1.w,gh1))));
        gh2 = fmaf(y0,b2.x,fmaf(y1,b2.y,fmaf(y2,b2.z,fmaf(y3,b2.w,gh2))));
      }
    }
    float r = sigf(gi0+gh0);
    float z = sigf(gi1+gh1);
    float nn = tanhf(gi2 + r*gh2);
    float hn = ((1.f - z)*nn + z*h0v)*mask;

    if (isLast){
      float sc = wsum(hn * wfv);
      if (lane==0) out[n] = sc;
      continue;
    }
    unsigned long long lv = __ballot(hn != 0.f);
    hid[base+lane] = hn;
    if (lane==0) liveB[n] = lv ? (u8)1 : (u8)0;

    // HS2 for next layer: h_new @ Ws[l+1]
    float acc = 0.f;
    #pragma unroll
    for (int h=0; h<HD; h+=4){
      float4 w = *(const float4*)(wsr + h);
      acc = fmaf(__shfl(hn,h  ,64), w.x, acc);
      acc = fmaf(__shfl(hn,h+1,64), w.y, acc);
      acc = fmaf(__shfl(hn,h+2,64), w.z, acc);
      acc = fmaf(__shfl(hn,h+3,64), w.w, acc);
    }
    HS2[base+lane] = acc;
  }
}

// -------- clear liveness of prev-live nodes that received no messages --------
__global__ void k_died(const int* __restrict__ plist, const int* __restrict__ pcnt,
                       const int* __restrict__ stamp, u8* __restrict__ liveB, int ep, int N)
{
  int cntv = pcnt[0]; if (cntv > N) cntv = N;
  int t = blockIdx.x*256 + threadIdx.x;
  for (int i = t; i < cntv; i += gridDim.x*256){
    int n = plist[i];
    if (stamp[n] != ep) liveB[n] = 0;
  }
}

extern "C" void kernel_launch(void* const* d_in, const int* in_sizes, int n_in,
                              void* d_out, int out_size, void* d_ws, size_t ws_size,
                              hipStream_t stream)
{
  const int* sub   = (const int*)d_in[0];
  const int* rel_i = (const int*)d_in[1];
  const int* obj   = (const int*)d_in[2];
  const int* eb    = (const int*)d_in[3];
  const int* q_rel = (const int*)d_in[4];
  const int* qsub  = (const int*)d_in[5];
  const void* rela = d_in[6];
  const void* qre  = d_in[7];
  const void* Wsp  = d_in[8];
  const void* Wr   = d_in[9];
  const void* Wqr  = d_in[10];
  const void* bqr  = d_in[11];
  const void* wal  = d_in[12];
  const void* bal  = d_in[13];
  const void* W_h  = d_in[14];
  const void* Wih  = d_in[15];
  const void* Whh  = d_in[16];
  const void* bih  = d_in[17];
  const void* bhh  = d_in[18];
  const void* Wf   = d_in[19];

  int E  = in_sizes[0];
  int B  = in_sizes[4];
  int NR = in_sizes[6]/(NL*HD);
  int N  = out_size;

  float* ws = (float*)d_ws;
  size_t o = 0;
  float* agg  = ws + o; o += (size_t)N*HD;     // memset to 0 each call
  float* hid  = ws + o; o += (size_t)N*HD;     // no memset (reads guarded by liveB)
  float* HS2  = ws + o; o += (size_t)N*HD;     // no memset (reads only for live subs)
  float* R2   = ws + o; o += (size_t)NL*NR*HD;
  float* QR   = ws + o; o += (size_t)NL*B*HD;
  float* REL  = ws + o; o += (size_t)NL*NR*HD;
  float* WhT  = ws + o; o += NL*HD*HD;
  float* WsT  = ws + o; o += NL*HD*HD;
  float* WihF = ws + o; o += NL*192*HD;
  float* WhhF = ws + o; o += NL*192*HD;
  float* biF  = ws + o; o += NL*192;
  float* bhF  = ws + o; o += NL*192;
  float* waF  = ws + o; o += NL*HD;
  float* baF  = ws + o; o += NL;
  float* WfF  = ws + o; o += HD;
  int*   elist= (int*)(ws + o); o += E;
  int*   listA= (int*)(ws + o); o += N;
  int*   listB= (int*)(ws + o); o += N;
  int*   stamp= (int*)(ws + o); o += N;        // ┐ contiguous memset region:
  int*   cnts = (int*)(ws + o); o += 16;       // │ stamp + cnts + liveB
  u8*    liveB= (u8*)(ws + o);                 // ┘ N bytes

  // cnts: [0..2]=live-edge counts, [3]=init live cnt, [4..6]=touched cnts, [8]=dtype flag
  hipMemsetAsync(agg,   0, (size_t)N*HD*sizeof(float), stream);
  hipMemsetAsync(stamp, 0, (size_t)N*sizeof(int) + 16*sizeof(int) + (size_t)N, stream);
  hipMemsetAsync(d_out, 0, (size_t)N*sizeof(float), stream);

  k_dtype<<<1, 64, 0, stream>>>((const unsigned short*)rela, cnts+8);

  int prepN = 2*(NL*HD*HD) + 2*(NL*192*HD) + 2*(NL*192) + NL*HD + NL + HD + NL*NR*HD;
  k_prep<<<(prepN+255)/256, 256, 0, stream>>>(W_h, Wsp, Wih, Whh, bih, bhh, wal, bal, Wf, rela,
      WhT, WsT, WihF, WhhF, biF, bhF, waF, baF, WfF, REL, cnts+8, NR);
  k_tables<<<NL*NR + NL*B, 64, 0, stream>>>(rela, Wr, Wqr, bqr, q_rel, R2, QR, cnts+8, NR, B);
  k_init<<<1, 64, 0, stream>>>(qsub, q_rel, qre, WsT, hid, HS2, liveB,
                               stamp, listA, cnts+3, cnts+8, B);

  int* curT = listB;   // touched list this layer
  int* prevL = listA;  // live list before this layer
  for (int l=0; l<NL; ++l){
    int ep = l + 2;
    k_filter<<<(E+255)/256, 256, 0, stream>>>(sub, liveB, elist, cnts+l, E);
    k_edge<<<2048, 256, 0, stream>>>(elist, cnts+l, sub, rel_i, obj, eb, hid, HS2,
        R2 + (size_t)l*NR*HD, QR + (size_t)l*B*HD, REL + (size_t)l*NR*HD,
        waF + l*HD, baF + l, agg, stamp, curT, cnts+4+l, ep, E);
    k_node<<<512, 256, 0, stream>>>(curT, cnts+4+l, agg, hid, HS2, liveB,
        WhT + (size_t)l*HD*HD, WihF + (size_t)l*192*HD, WhhF + (size_t)l*192*HD,
        biF + l*192, bhF + l*192,
        (l < NL-1) ? (WsT + (size_t)(l+1)*HD*HD) : WsT,
        WfF, (float*)d_out, N, (l==0)?1:0, (l==NL-1)?1:0);
    if (l < NL-1){
      k_died<<<64, 256, 0, stream>>>(prevL, (l==0) ? (cnts+3) : (cnts+4+l-1),
                                     stamp, liveB, ep, N);
    }
    int* t = prevL; prevL = curT; curT = t;
  }
}

// Round 5
// 399.039 us; speedup vs baseline: 2.4881x; 2.4881x over previous
//
#include <hip/hip_runtime.h>
#include <hip/hip_bf16.h>

#define NL 3
#define HD 64
#define TCAP 2048

typedef unsigned char u8;

__device__ __forceinline__ float sigf(float x){ return 1.f/(1.f+__expf(-x)); }

__device__ __forceinline__ float wsum(float v){
  #pragma unroll
  for (int off=32; off; off>>=1) v += __shfl_xor(v, off, 64);
  return v;
}

// dtype-flexible load: bf==1 -> bf16, bf==0 -> f32
__device__ __forceinline__ float ldin(const void* p, size_t i, int bf){
  return bf ? __bfloat162float(((const __hip_bfloat16*)p)[i]) : ((const float*)p)[i];
}

// -------- runtime dtype probe: bf16 halves of N(0,0.05) data have sane exponents --------
__global__ void k_dtype(const unsigned short* __restrict__ probe, int* __restrict__ flag){
  int lane = threadIdx.x & 63;
  unsigned short h = probe[lane];
  int e = (h >> 7) & 0xFF;
  int sane = ((h & 0x7FFF) == 0) || (e >= 96 && e <= 132);
  unsigned long long m = __ballot(sane != 0);
  if (lane == 0) flag[0] = (__popcll(m) >= 56) ? 1 : 0;
}

// -------- convert/transpose all weights into f32 scratch --------
__global__ void k_prep(
    const void* __restrict__ W_h, const void* __restrict__ Ws,
    const void* __restrict__ Wih, const void* __restrict__ Whh,
    const void* __restrict__ bih, const void* __restrict__ bhh,
    const void* __restrict__ wal, const void* __restrict__ bal,
    const void* __restrict__ Wf,  const void* __restrict__ rel,
    float* __restrict__ WhT, float* __restrict__ WsT,
    float* __restrict__ WihF, float* __restrict__ WhhF,
    float* __restrict__ biF, float* __restrict__ bhF,
    float* __restrict__ waF, float* __restrict__ baF,
    float* __restrict__ WfF, float* __restrict__ REL,
    const int* __restrict__ flag, int NR)
{
  int bf = flag[0];
  int j = blockIdx.x*256 + threadIdx.x;
  const int sWT = NL*HD*HD, sWI = NL*192*HD, sB = NL*192;
  if (j < sWT){ int l=j/(HD*HD), q=j%(HD*HD), a=q/HD, h=q%HD; WhT[j]=ldin(W_h,(size_t)(l*HD+h)*HD+a,bf); return; } j-=sWT;
  if (j < sWT){ int l=j/(HD*HD), q=j%(HD*HD), a=q/HD, h=q%HD; WsT[j]=ldin(Ws ,(size_t)(l*HD+h)*HD+a,bf); return; } j-=sWT;
  if (j < sWI){ WihF[j]=ldin(Wih,j,bf); return; } j-=sWI;
  if (j < sWI){ WhhF[j]=ldin(Whh,j,bf); return; } j-=sWI;
  if (j < sB){ biF[j]=ldin(bih,j,bf); return; } j-=sB;
  if (j < sB){ bhF[j]=ldin(bhh,j,bf); return; } j-=sB;
  if (j < NL*HD){ waF[j]=ldin(wal,j,bf); return; } j-=NL*HD;
  if (j < NL){ baF[j]=ldin(bal,j,bf); return; } j-=NL;
  if (j < HD){ WfF[j]=ldin(Wf,j,bf); return; } j-=HD;
  if (j < NL*NR*HD){ REL[j]=ldin(rel,j,bf); return; }
}

// -------- per-(layer,rel) hr@Wr and per-(layer,batch) h_qr@Wqr+bqr tables --------
__global__ void k_tables(
    const void* __restrict__ rel, const void* __restrict__ Wr,
    const void* __restrict__ Wqr, const void* __restrict__ bqr,
    const int* __restrict__ q_rel,
    float* __restrict__ R2, float* __restrict__ QR,
    const int* __restrict__ flag, int NR, int B)
{
  int bf = flag[0];
  int lane = threadIdx.x & 63;
  int bid = blockIdx.x;
  if (bid < NL*NR){
    int l = bid/NR, r = bid%NR;
    float x = ldin(rel,(size_t)(l*NR+r)*HD + lane,bf);
    float acc = 0.f;
    #pragma unroll
    for (int h=0; h<HD; ++h)
      acc = fmaf(__shfl(x, h, 64), ldin(Wr,(size_t)(l*HD+h)*HD + lane,bf), acc);
    R2[(size_t)bid*HD + lane] = acc;
  } else {
    int b2 = bid - NL*NR;
    int l = b2/B, b = b2%B;
    int r = q_rel[b];
    float x = ldin(rel,(size_t)(l*NR+r)*HD + lane,bf);
    float acc = ldin(bqr,(size_t)l*HD + lane,bf);
    #pragma unroll
    for (int h=0; h<HD; ++h)
      acc = fmaf(__shfl(x, h, 64), ldin(Wqr,(size_t)(l*HD+h)*HD + lane,bf), acc);
    QR[(size_t)b2*HD + lane] = acc;
  }
}

// -------- seed query nodes; build initial live list; HS2 = hid @ Ws[0] --------
__global__ void k_init(
    const int* __restrict__ qsub, const int* __restrict__ q_rel,
    const void* __restrict__ qre, const float* __restrict__ WsT0,
    float* __restrict__ hid, float* __restrict__ HS2, u8* __restrict__ liveB,
    int* __restrict__ stamp, int* __restrict__ plist, int* __restrict__ pcnt,
    const int* __restrict__ flag, int B)
{
  int bf = flag[0];
  int lane = threadIdx.x & 63;
  const float* __restrict__ wsr = WsT0 + (size_t)lane*HD;
  int pc = 0;
  for (int b=0; b<B; ++b){
    int n = qsub[b];
    int r = q_rel[b];
    float v = ldin(qre,(size_t)r*HD + lane,bf);
    hid[(size_t)n*HD + lane] = v;               // last write wins (np .at[].set)
    float acc = 0.f;
    #pragma unroll
    for (int h=0; h<HD; h+=4){
      float4 w = *(const float4*)(wsr + h);
      acc = fmaf(__shfl(v,h  ,64), w.x, acc);
      acc = fmaf(__shfl(v,h+1,64), w.y, acc);
      acc = fmaf(__shfl(v,h+2,64), w.z, acc);
      acc = fmaf(__shfl(v,h+3,64), w.w, acc);
    }
    HS2[(size_t)n*HD + lane] = acc;
    if (lane==0){
      liveB[n] = 1;
      if (stamp[n] != 1){ stamp[n] = 1; plist[pc++] = n; }
    }
  }
  if (lane==0) pcnt[0] = pc;
}

// -------- fused edge phase: scan ALL edges (64/wave/step), process live via ballot;
//          touched-node appends buffered in LDS, one global atomic per block --------
__global__ void __launch_bounds__(256) k_edge(
    const int* __restrict__ sub, const int* __restrict__ rel_i,
    const int* __restrict__ obj, const int* __restrict__ eb,
    const u8* __restrict__ liveB,
    const float* __restrict__ hid, const float* __restrict__ HS2,
    const float* __restrict__ R2l, const float* __restrict__ QRl,
    const float* __restrict__ RELl, const float* __restrict__ waFl,
    const float* __restrict__ baFl, float* __restrict__ agg,
    int* __restrict__ stamp, int* __restrict__ tlist, int* __restrict__ tcnt,
    int ep, int E)
{
  __shared__ int s_cnt;
  __shared__ int s_base;
  __shared__ int s_buf[TCAP];
  if (threadIdx.x == 0) s_cnt = 0;
  __syncthreads();

  int lane = threadIdx.x & 63;
  int wid = (blockIdx.x*256 + threadIdx.x) >> 6;
  int nw = gridDim.x*4;
  float wa = waFl[lane];
  float ba = baFl[0];

  for (long long base = (long long)wid*64; base < E; base += (long long)nw*64){
    int e = (int)base + lane;
    int s = (e < E) ? sub[e] : 0;
    bool liv = (e < E) && (liveB[s] != 0);
    unsigned long long mask = __ballot(liv);
    while (mask){
      int bit = (int)__ffsll(mask) - 1;
      mask &= mask - 1;
      int ee = (int)base + bit;
      int ss = sub[ee], r = rel_i[ee], o = obj[ee], b = eb[ee];  // wave-uniform, L1-hot
      float hs  = hid[(size_t)ss*HD + lane];
      float pre = HS2[(size_t)ss*HD + lane] + R2l[(size_t)r*HD + lane] + QRl[(size_t)b*HD + lane];
      pre = fmaxf(pre, 0.f);
      float d = wsum(pre*wa) + ba;
      float alpha = sigf(d);
      float msg = alpha * hs * RELl[(size_t)r*HD + lane];
      unsafeAtomicAdd(&agg[(size_t)o*HD + lane], msg);
      if (lane==0){
        int old = atomicExch(&stamp[o], ep);
        if (old != ep){
          int li = atomicAdd(&s_cnt, 1);
          if (li < TCAP) s_buf[li] = o;
          else { int gi = atomicAdd(tcnt, 1); tlist[gi] = o; }  // overflow guard
        }
      }
    }
  }

  __syncthreads();
  int cnt = s_cnt; if (cnt > TCAP) cnt = TCAP;
  if (threadIdx.x == 0 && cnt > 0) s_base = atomicAdd(tcnt, cnt);
  __syncthreads();
  if (cnt > 0){
    int b0 = s_base;
    for (int i = threadIdx.x; i < cnt; i += 256) tlist[b0 + i] = s_buf[i];
  }
}

// -------- node phase over TOUCHED nodes only; epilogue computes next HS2 --------
__global__ void __launch_bounds__(256) k_node(
    const int* __restrict__ tlist, const int* __restrict__ tcnt,
    float* __restrict__ agg, float* __restrict__ hid, float* __restrict__ HS2,
    u8* __restrict__ liveB,
    const float* __restrict__ WhTl, const float* __restrict__ WihFl,
    const float* __restrict__ WhhFl, const float* __restrict__ biFl,
    const float* __restrict__ bhFl, const float* __restrict__ WsTn,
    const float* __restrict__ WfF,
    float* __restrict__ out, int N, int isFirst, int isLast)
{
  int cntv = tcnt[0]; if (cntv > N) cntv = N;
  int lane = threadIdx.x & 63;
  int wid = (blockIdx.x*256 + threadIdx.x) >> 6;
  int nw = gridDim.x*4;
  float bi0=biFl[lane], bi1=biFl[HD+lane], bi2=biFl[2*HD+lane];
  float bh0=bhFl[lane], bh1=bhFl[HD+lane], bh2=bhFl[2*HD+lane];
  float wfv = isLast ? WfF[lane] : 0.f;
  const float* __restrict__ wrow = WhTl + (size_t)lane*HD;
  const float* __restrict__ wi0 = WihFl + (size_t)lane*HD;
  const float* __restrict__ wi1 = WihFl + (size_t)(HD+lane)*HD;
  const float* __restrict__ wi2 = WihFl + (size_t)(2*HD+lane)*HD;
  const float* __restrict__ wh0 = WhhFl + (size_t)lane*HD;
  const float* __restrict__ wh1 = WhhFl + (size_t)(HD+lane)*HD;
  const float* __restrict__ wh2 = WhhFl + (size_t)(2*HD+lane)*HD;
  const float* __restrict__ wsr = WsTn + (size_t)lane*HD;

  for (int i = wid; i < cntv; i += nw){
    int n = tlist[i];
    size_t base = (size_t)n*HD;
    float av = agg[base+lane];
    agg[base+lane] = 0.f;             // restore zeros for next layer's atomics

    // h_mid = relu(agg @ W_h)
    float hm = 0.f;
    #pragma unroll
    for (int h=0; h<HD; h+=4){
      float4 w = *(const float4*)(wrow + h);
      hm = fmaf(__shfl(av,h  ,64), w.x, hm);
      hm = fmaf(__shfl(av,h+1,64), w.y, hm);
      hm = fmaf(__shfl(av,h+2,64), w.z, hm);
      hm = fmaf(__shfl(av,h+3,64), w.w, hm);
    }
    hm = fmaxf(hm, 0.f);
    float mask = (__ballot(hm != 0.f) != 0ull) ? 1.f : 0.f;
    bool wasLive = !isFirst && (liveB[n] != 0);
    float h0v = wasLive ? hid[base+lane] : 0.f;

    float gi0=bi0, gi1=bi1, gi2=bi2;
    float gh0=bh0, gh1=bh1, gh2=bh2;
    #pragma unroll
    for (int h=0; h<HD; h+=4){
      float x0=__shfl(hm,h,64), x1=__shfl(hm,h+1,64), x2=__shfl(hm,h+2,64), x3=__shfl(hm,h+3,64);
      float4 a0 = *(const float4*)(wi0+h);
      float4 a1 = *(const float4*)(wi1+h);
      float4 a2 = *(const float4*)(wi2+h);
      gi0 = fmaf(x0,a0.x,fmaf(x1,a0.y,fmaf(x2,a0.z,fmaf(x3,a0.w,gi0))));
      gi1 = fmaf(x0,a1.x,fmaf(x1,a1.y,fmaf(x2,a1.z,fmaf(x3,a1.w,gi1))));
      gi2 = fmaf(x0,a2.x,fmaf(x1,a2.y,fmaf(x2,a2.z,fmaf(x3,a2.w,gi2))));
    }
    if (wasLive){
      #pragma unroll
      for (int h=0; h<HD; h+=4){
        float y0=__shfl(h0v,h,64), y1=__shfl(h0v,h+1,64), y2=__shfl(h0v,h+2,64), y3=__shfl(h0v,h+3,64);
        float4 b0 = *(const float4*)(wh0+h);
        float4 b1 = *(const float4*)(wh1+h);
        float4 b2 = *(const float4*)(wh2+h);
        gh0 = fmaf(y0,b0.x,fmaf(y1,b0.y,fmaf(y2,b0.z,fmaf(y3,b0.w,gh0))));
        gh1 = fmaf(y0,b1.x,fmaf(y1,b1.y,fmaf(y2,b1.z,fmaf(y3,b1.w,gh1))));
        gh2 = fmaf(y0,b2.x,fmaf(y1,b2.y,fmaf(y2,b2.z,fmaf(y3,b2.w,gh2))));
      }
    }
    float r = sigf(gi0+gh0);
    float z = sigf(gi1+gh1);
    float nn = tanhf(gi2 + r*gh2);
    float hn = ((1.f - z)*nn + z*h0v)*mask;

    if (isLast){
      float sc = wsum(hn * wfv);
      if (lane==0) out[n] = sc;
      continue;
    }
    unsigned long long lv = __ballot(hn != 0.f);
    hid[base+lane] = hn;
    if (lane==0) liveB[n] = lv ? (u8)1 : (u8)0;

    // HS2 for next layer: h_new @ Ws[l+1]
    float acc = 0.f;
    #pragma unroll
    for (int h=0; h<HD; h+=4){
      float4 w = *(const float4*)(wsr + h);
      acc = fmaf(__shfl(hn,h  ,64), w.x, acc);
      acc = fmaf(__shfl(hn,h+1,64), w.y, acc);
      acc = fmaf(__shfl(hn,h+2,64), w.z, acc);
      acc = fmaf(__shfl(hn,h+3,64), w.w, acc);
    }
    HS2[base+lane] = acc;
  }
}

// -------- clear liveness of prev-live nodes that received no messages --------
__global__ void k_died(const int* __restrict__ plist, const int* __restrict__ pcnt,
                       const int* __restrict__ stamp, u8* __restrict__ liveB, int ep, int N)
{
  int cntv = pcnt[0]; if (cntv > N) cntv = N;
  int t = blockIdx.x*256 + threadIdx.x;
  for (int i = t; i < cntv; i += gridDim.x*256){
    int n = plist[i];
    if (stamp[n] != ep) liveB[n] = 0;
  }
}

extern "C" void kernel_launch(void* const* d_in, const int* in_sizes, int n_in,
                              void* d_out, int out_size, void* d_ws, size_t ws_size,
                              hipStream_t stream)
{
  const int* sub   = (const int*)d_in[0];
  const int* rel_i = (const int*)d_in[1];
  const int* obj   = (const int*)d_in[2];
  const int* eb    = (const int*)d_in[3];
  const int* q_rel = (const int*)d_in[4];
  const int* qsub  = (const int*)d_in[5];
  const void* rela = d_in[6];
  const void* qre  = d_in[7];
  const void* Wsp  = d_in[8];
  const void* Wr   = d_in[9];
  const void* Wqr  = d_in[10];
  const void* bqr  = d_in[11];
  const void* wal  = d_in[12];
  const void* bal  = d_in[13];
  const void* W_h  = d_in[14];
  const void* Wih  = d_in[15];
  const void* Whh  = d_in[16];
  const void* bih  = d_in[17];
  const void* bhh  = d_in[18];
  const void* Wf   = d_in[19];

  int E  = in_sizes[0];
  int B  = in_sizes[4];
  int NR = in_sizes[6]/(NL*HD);
  int N  = out_size;

  float* ws = (float*)d_ws;
  size_t o = 0;
  float* agg  = ws + o; o += (size_t)N*HD;     // memset to 0 each call
  float* hid  = ws + o; o += (size_t)N*HD;     // no memset (reads guarded by liveB)
  float* HS2  = ws + o; o += (size_t)N*HD;     // no memset (reads only for live subs)
  float* R2   = ws + o; o += (size_t)NL*NR*HD;
  float* QR   = ws + o; o += (size_t)NL*B*HD;
  float* REL  = ws + o; o += (size_t)NL*NR*HD;
  float* WhT  = ws + o; o += NL*HD*HD;
  float* WsT  = ws + o; o += NL*HD*HD;
  float* WihF = ws + o; o += NL*192*HD;
  float* WhhF = ws + o; o += NL*192*HD;
  float* biF  = ws + o; o += NL*192;
  float* bhF  = ws + o; o += NL*192;
  float* waF  = ws + o; o += NL*HD;
  float* baF  = ws + o; o += NL;
  float* WfF  = ws + o; o += HD;
  int*   listA= (int*)(ws + o); o += N;
  int*   listB= (int*)(ws + o); o += N;
  int*   stamp= (int*)(ws + o); o += N;        // ┐ contiguous memset region:
  int*   cnts = (int*)(ws + o); o += 16;       // │ stamp + cnts + liveB
  u8*    liveB= (u8*)(ws + o);                 // ┘ N bytes

  // cnts: [3]=init live cnt, [4..6]=touched cnts, [8]=dtype flag
  hipMemsetAsync(agg,   0, (size_t)N*HD*sizeof(float), stream);
  hipMemsetAsync(stamp, 0, (size_t)N*sizeof(int) + 16*sizeof(int) + (size_t)N, stream);
  hipMemsetAsync(d_out, 0, (size_t)N*sizeof(float), stream);

  k_dtype<<<1, 64, 0, stream>>>((const unsigned short*)rela, cnts+8);

  int prepN = 2*(NL*HD*HD) + 2*(NL*192*HD) + 2*(NL*192) + NL*HD + NL + HD + NL*NR*HD;
  k_prep<<<(prepN+255)/256, 256, 0, stream>>>(W_h, Wsp, Wih, Whh, bih, bhh, wal, bal, Wf, rela,
      WhT, WsT, WihF, WhhF, biF, bhF, waF, baF, WfF, REL, cnts+8, NR);
  k_tables<<<NL*NR + NL*B, 64, 0, stream>>>(rela, Wr, Wqr, bqr, q_rel, R2, QR, cnts+8, NR, B);
  k_init<<<1, 64, 0, stream>>>(qsub, q_rel, qre, WsT, hid, HS2, liveB,
                               stamp, listA, cnts+3, cnts+8, B);

  int* curT = listB;   // touched list this layer
  int* prevL = listA;  // live list before this layer
  for (int l=0; l<NL; ++l){
    int ep = l + 2;
    k_edge<<<512, 256, 0, stream>>>(sub, rel_i, obj, eb, liveB, hid, HS2,
        R2 + (size_t)l*NR*HD, QR + (size_t)l*B*HD, REL + (size_t)l*NR*HD,
        waF + l*HD, baF + l, agg, stamp, curT, cnts+4+l, ep, E);
    k_node<<<512, 256, 0, stream>>>(curT, cnts+4+l, agg, hid, HS2, liveB,
        WhT + (size_t)l*HD*HD, WihF + (size_t)l*192*HD, WhhF + (size_t)l*192*HD,
        biF + l*192, bhF + l*192,
        (l < NL-1) ? (WsT + (size_t)(l+1)*HD*HD) : WsT,
        WfF, (float*)d_out, N, (l==0)?1:0, (l==NL-1)?1:0);
    if (l < NL-1){
      k_died<<<64, 256, 0, stream>>>(prevL, (l==0) ? (cnts+3) : (cnts+4+l-1),
                                     stamp, liveB, ep, N);
    }
    int* t = prevL; prevL = curT; curT = t;
  }
}

// Round 6
// 257.540 us; speedup vs baseline: 3.8552x; 1.5494x over previous
//
#include <hip/hip_runtime.h>
#include <hip/hip_bf16.h>

#define NL 3
#define HD 64
#define TCAP 2048

typedef unsigned char u8;

__device__ __forceinline__ float sigf(float x){ return 1.f/(1.f+__expf(-x)); }

__device__ __forceinline__ float wsum(float v){
  #pragma unroll
  for (int off=32; off; off>>=1) v += __shfl_xor(v, off, 64);
  return v;
}

// dtype-flexible load: bf==1 -> bf16, bf==0 -> f32
__device__ __forceinline__ float ldin(const void* p, size_t i, int bf){
  return bf ? __bfloat162float(((const __hip_bfloat16*)p)[i]) : ((const float*)p)[i];
}

// -------- runtime dtype probe: bf16 halves of N(0,0.05) data have sane exponents --------
__global__ void k_dtype(const unsigned short* __restrict__ probe, int* __restrict__ flag){
  int lane = threadIdx.x & 63;
  unsigned short h = probe[lane];
  int e = (h >> 7) & 0xFF;
  int sane = ((h & 0x7FFF) == 0) || (e >= 96 && e <= 132);
  unsigned long long m = __ballot(sane != 0);
  if (lane == 0) flag[0] = (__popcll(m) >= 56) ? 1 : 0;
}

// -------- convert weights to f32 scratch.
// All matvec weights end up INPUT-MAJOR [h][a] so lane=a loads are coalesced:
//   WhF, WsF : plain copies of W_h, Ws           [l][h][a]
//   WiT, WhT : transposed Wih, Whh               [l][h][3H]
__global__ void k_prep(
    const void* __restrict__ W_h, const void* __restrict__ Ws,
    const void* __restrict__ Wih, const void* __restrict__ Whh,
    const void* __restrict__ bih, const void* __restrict__ bhh,
    const void* __restrict__ wal, const void* __restrict__ bal,
    const void* __restrict__ Wf,  const void* __restrict__ rel,
    float* __restrict__ WhF, float* __restrict__ WsF,
    float* __restrict__ WiT, float* __restrict__ WhT,
    float* __restrict__ biF, float* __restrict__ bhF,
    float* __restrict__ waF, float* __restrict__ baF,
    float* __restrict__ WfF, float* __restrict__ REL,
    const int* __restrict__ flag, int NR)
{
  int bf = flag[0];
  int j = blockIdx.x*256 + threadIdx.x;
  const int sWT = NL*HD*HD, sWI = NL*192*HD, sB = NL*192;
  if (j < sWT){ WhF[j]=ldin(W_h,j,bf); return; } j-=sWT;
  if (j < sWT){ WsF[j]=ldin(Ws ,j,bf); return; } j-=sWT;
  if (j < sWI){ int l=j/(192*HD), q=j%(192*HD), h=q/192, a=q%192;
                WiT[j]=ldin(Wih,(size_t)l*192*HD + (size_t)a*HD + h,bf); return; } j-=sWI;
  if (j < sWI){ int l=j/(192*HD), q=j%(192*HD), h=q/192, a=q%192;
                WhT[j]=ldin(Whh,(size_t)l*192*HD + (size_t)a*HD + h,bf); return; } j-=sWI;
  if (j < sB){ biF[j]=ldin(bih,j,bf); return; } j-=sB;
  if (j < sB){ bhF[j]=ldin(bhh,j,bf); return; } j-=sB;
  if (j < NL*HD){ waF[j]=ldin(wal,j,bf); return; } j-=NL*HD;
  if (j < NL){ baF[j]=ldin(bal,j,bf); return; } j-=NL;
  if (j < HD){ WfF[j]=ldin(Wf,j,bf); return; } j-=HD;
  if (j < NL*NR*HD){ REL[j]=ldin(rel,j,bf); return; }
}

// -------- per-(layer,rel) hr@Wr and per-(layer,batch) h_qr@Wqr+bqr tables --------
__global__ void k_tables(
    const void* __restrict__ rel, const void* __restrict__ Wr,
    const void* __restrict__ Wqr, const void* __restrict__ bqr,
    const int* __restrict__ q_rel,
    float* __restrict__ R2, float* __restrict__ QR,
    const int* __restrict__ flag, int NR, int B)
{
  int bf = flag[0];
  int lane = threadIdx.x & 63;
  int bid = blockIdx.x;
  if (bid < NL*NR){
    int l = bid/NR, r = bid%NR;
    float x = ldin(rel,(size_t)(l*NR+r)*HD + lane,bf);
    float acc = 0.f;
    #pragma unroll
    for (int h=0; h<HD; ++h)
      acc = fmaf(__shfl(x, h, 64), ldin(Wr,(size_t)(l*HD+h)*HD + lane,bf), acc);
    R2[(size_t)bid*HD + lane] = acc;
  } else {
    int b2 = bid - NL*NR;
    int l = b2/B, b = b2%B;
    int r = q_rel[b];
    float x = ldin(rel,(size_t)(l*NR+r)*HD + lane,bf);
    float acc = ldin(bqr,(size_t)l*HD + lane,bf);
    #pragma unroll
    for (int h=0; h<HD; ++h)
      acc = fmaf(__shfl(x, h, 64), ldin(Wqr,(size_t)(l*HD+h)*HD + lane,bf), acc);
    QR[(size_t)b2*HD + lane] = acc;
  }
}

// -------- seed query nodes; build initial live list; HS2 = hid @ Ws[0] --------
__global__ void k_init(
    const int* __restrict__ qsub, const int* __restrict__ q_rel,
    const void* __restrict__ qre, const float* __restrict__ WsF0,
    float* __restrict__ hid, float* __restrict__ HS2, u8* __restrict__ liveB,
    int* __restrict__ stamp, int* __restrict__ plist, int* __restrict__ pcnt,
    const int* __restrict__ flag, int B)
{
  int bf = flag[0];
  int lane = threadIdx.x & 63;
  int pc = 0;
  for (int b=0; b<B; ++b){
    int n = qsub[b];
    int r = q_rel[b];
    float v = ldin(qre,(size_t)r*HD + lane,bf);
    hid[(size_t)n*HD + lane] = v;               // last write wins (np .at[].set)
    float acc = 0.f;
    #pragma unroll 8
    for (int h=0; h<HD; ++h)
      acc = fmaf(__shfl(v,h,64), WsF0[h*HD + lane], acc);
    HS2[(size_t)n*HD + lane] = acc;
    if (lane==0){
      liveB[n] = 1;
      if (stamp[n] != 1){ stamp[n] = 1; plist[pc++] = n; }
    }
  }
  if (lane==0) pcnt[0] = pc;
}

// -------- fused edge phase: scan ALL edges (64/wave/step), process live via ballot;
//          touched-node appends buffered in LDS, one global atomic per block --------
__global__ void __launch_bounds__(256) k_edge(
    const int* __restrict__ sub, const int* __restrict__ rel_i,
    const int* __restrict__ obj, const int* __restrict__ eb,
    const u8* __restrict__ liveB,
    const float* __restrict__ hid, const float* __restrict__ HS2,
    const float* __restrict__ R2l, const float* __restrict__ QRl,
    const float* __restrict__ RELl, const float* __restrict__ waFl,
    const float* __restrict__ baFl, float* __restrict__ agg,
    int* __restrict__ stamp, int* __restrict__ tlist, int* __restrict__ tcnt,
    int ep, int E)
{
  __shared__ int s_cnt;
  __shared__ int s_base;
  __shared__ int s_buf[TCAP];
  if (threadIdx.x == 0) s_cnt = 0;
  __syncthreads();

  int lane = threadIdx.x & 63;
  int wid = (blockIdx.x*256 + threadIdx.x) >> 6;
  int nw = gridDim.x*4;
  float wa = waFl[lane];
  float ba = baFl[0];

  for (long long base = (long long)wid*64; base < E; base += (long long)nw*64){
    int e = (int)base + lane;
    int s = (e < E) ? sub[e] : 0;
    bool liv = (e < E) && (liveB[s] != 0);
    unsigned long long mask = __ballot(liv);
    while (mask){
      int bit = (int)__ffsll(mask) - 1;
      mask &= mask - 1;
      int ee = (int)base + bit;
      int ss = sub[ee], r = rel_i[ee], o = obj[ee], b = eb[ee];  // wave-uniform, L1-hot
      float hs  = hid[(size_t)ss*HD + lane];
      float pre = HS2[(size_t)ss*HD + lane] + R2l[(size_t)r*HD + lane] + QRl[(size_t)b*HD + lane];
      pre = fmaxf(pre, 0.f);
      float d = wsum(pre*wa) + ba;
      float alpha = sigf(d);
      float msg = alpha * hs * RELl[(size_t)r*HD + lane];
      unsafeAtomicAdd(&agg[(size_t)o*HD + lane], msg);
      if (lane==0){
        int old = atomicExch(&stamp[o], ep);
        if (old != ep){
          int li = atomicAdd(&s_cnt, 1);
          if (li < TCAP) s_buf[li] = o;
          else { int gi = atomicAdd(tcnt, 1); tlist[gi] = o; }  // overflow guard
        }
      }
    }
  }

  __syncthreads();
  int cnt = s_cnt; if (cnt > TCAP) cnt = TCAP;
  if (threadIdx.x == 0 && cnt > 0) s_base = atomicAdd(tcnt, cnt);
  __syncthreads();
  if (cnt > 0){
    int b0 = s_base;
    for (int i = threadIdx.x; i < cnt; i += 256) tlist[b0 + i] = s_buf[i];
  }
}

// -------- node phase over TOUCHED nodes only; all weight loads coalesced --------
__global__ void __launch_bounds__(256) k_node(
    const int* __restrict__ tlist, const int* __restrict__ tcnt,
    float* __restrict__ agg, float* __restrict__ hid, float* __restrict__ HS2,
    u8* __restrict__ liveB,
    const float* __restrict__ WhFl,  // [H][H]
    const float* __restrict__ WiTl,  // [H][3H]
    const float* __restrict__ WhTl,  // [H][3H]
    const float* __restrict__ biFl, const float* __restrict__ bhFl,
    const float* __restrict__ WsFn,  // [H][H] (next layer)
    const float* __restrict__ WfF,
    float* __restrict__ out, int N, int isFirst, int isLast)
{
  int cntv = tcnt[0]; if (cntv > N) cntv = N;
  int lane = threadIdx.x & 63;
  int wid = (blockIdx.x*256 + threadIdx.x) >> 6;
  int nw = gridDim.x*4;
  float bi0=biFl[lane], bi1=biFl[HD+lane], bi2=biFl[2*HD+lane];
  float bh0=bhFl[lane], bh1=bhFl[HD+lane], bh2=bhFl[2*HD+lane];
  float wfv = isLast ? WfF[lane] : 0.f;

  for (int i = wid; i < cntv; i += nw){
    int n = tlist[i];
    size_t base = (size_t)n*HD;
    float av = agg[base+lane];
    agg[base+lane] = 0.f;             // restore zeros for next layer's atomics

    // h_mid = relu(agg @ W_h)  — 4 independent accumulator chains
    float hm0=0.f, hm1=0.f, hm2=0.f, hm3=0.f;
    #pragma unroll 4
    for (int h=0; h<HD; h+=4){
      hm0 = fmaf(__shfl(av,h  ,64), WhFl[(h  )*HD+lane], hm0);
      hm1 = fmaf(__shfl(av,h+1,64), WhFl[(h+1)*HD+lane], hm1);
      hm2 = fmaf(__shfl(av,h+2,64), WhFl[(h+2)*HD+lane], hm2);
      hm3 = fmaf(__shfl(av,h+3,64), WhFl[(h+3)*HD+lane], hm3);
    }
    float hm = fmaxf((hm0+hm1)+(hm2+hm3), 0.f);
    float mask = (__ballot(hm != 0.f) != 0ull) ? 1.f : 0.f;
    bool wasLive = !isFirst && (liveB[n] != 0);
    float h0v = wasLive ? hid[base+lane] : 0.f;

    float gi0=bi0, gi1=bi1, gi2=bi2;
    float gh0=bh0, gh1=bh1, gh2=bh2;
    #pragma unroll 4
    for (int h=0; h<HD; ++h){
      float x = __shfl(hm,h,64);
      const float* __restrict__ wr = WiTl + (size_t)h*192;
      gi0 = fmaf(x, wr[lane], gi0);
      gi1 = fmaf(x, wr[64+lane], gi1);
      gi2 = fmaf(x, wr[128+lane], gi2);
    }
    if (wasLive){
      #pragma unroll 4
      for (int h=0; h<HD; ++h){
        float y = __shfl(h0v,h,64);
        const float* __restrict__ wr = WhTl + (size_t)h*192;
        gh0 = fmaf(y, wr[lane], gh0);
        gh1 = fmaf(y, wr[64+lane], gh1);
        gh2 = fmaf(y, wr[128+lane], gh2);
      }
    }
    float r = sigf(gi0+gh0);
    float z = sigf(gi1+gh1);
    float nn = tanhf(gi2 + r*gh2);
    float hn = ((1.f - z)*nn + z*h0v)*mask;

    if (isLast){
      float sc = wsum(hn * wfv);
      if (lane==0) out[n] = sc;
      continue;
    }
    unsigned long long lv = __ballot(hn != 0.f);
    hid[base+lane] = hn;
    if (lane==0) liveB[n] = lv ? (u8)1 : (u8)0;

    // HS2 for next layer: h_new @ Ws[l+1] — 4 chains, coalesced loads
    float a0=0.f, a1=0.f, a2=0.f, a3=0.f;
    #pragma unroll 4
    for (int h=0; h<HD; h+=4){
      a0 = fmaf(__shfl(hn,h  ,64), WsFn[(h  )*HD+lane], a0);
      a1 = fmaf(__shfl(hn,h+1,64), WsFn[(h+1)*HD+lane], a1);
      a2 = fmaf(__shfl(hn,h+2,64), WsFn[(h+2)*HD+lane], a2);
      a3 = fmaf(__shfl(hn,h+3,64), WsFn[(h+3)*HD+lane], a3);
    }
    HS2[base+lane] = (a0+a1)+(a2+a3);
  }
}

// -------- clear liveness of prev-live nodes that received no messages --------
__global__ void k_died(const int* __restrict__ plist, const int* __restrict__ pcnt,
                       const int* __restrict__ stamp, u8* __restrict__ liveB, int ep, int N)
{
  int cntv = pcnt[0]; if (cntv > N) cntv = N;
  int t = blockIdx.x*256 + threadIdx.x;
  for (int i = t; i < cntv; i += gridDim.x*256){
    int n = plist[i];
    if (stamp[n] != ep) liveB[n] = 0;
  }
}

extern "C" void kernel_launch(void* const* d_in, const int* in_sizes, int n_in,
                              void* d_out, int out_size, void* d_ws, size_t ws_size,
                              hipStream_t stream)
{
  const int* sub   = (const int*)d_in[0];
  const int* rel_i = (const int*)d_in[1];
  const int* obj   = (const int*)d_in[2];
  const int* eb    = (const int*)d_in[3];
  const int* q_rel = (const int*)d_in[4];
  const int* qsub  = (const int*)d_in[5];
  const void* rela = d_in[6];
  const void* qre  = d_in[7];
  const void* Wsp  = d_in[8];
  const void* Wr   = d_in[9];
  const void* Wqr  = d_in[10];
  const void* bqr  = d_in[11];
  const void* wal  = d_in[12];
  const void* bal  = d_in[13];
  const void* W_h  = d_in[14];
  const void* Wih  = d_in[15];
  const void* Whh  = d_in[16];
  const void* bih  = d_in[17];
  const void* bhh  = d_in[18];
  const void* Wf   = d_in[19];

  int E  = in_sizes[0];
  int B  = in_sizes[4];
  int NR = in_sizes[6]/(NL*HD);
  int N  = out_size;

  float* ws = (float*)d_ws;
  size_t o = 0;
  float* agg  = ws + o; o += (size_t)N*HD;     // memset to 0 each call
  float* hid  = ws + o; o += (size_t)N*HD;     // no memset (reads guarded by liveB)
  float* HS2  = ws + o; o += (size_t)N*HD;     // no memset (reads only for live subs)
  float* R2   = ws + o; o += (size_t)NL*NR*HD;
  float* QR   = ws + o; o += (size_t)NL*B*HD;
  float* REL  = ws + o; o += (size_t)NL*NR*HD;
  float* WhF  = ws + o; o += NL*HD*HD;
  float* WsF  = ws + o; o += NL*HD*HD;
  float* WiT  = ws + o; o += NL*192*HD;
  float* WhT  = ws + o; o += NL*192*HD;
  float* biF  = ws + o; o += NL*192;
  float* bhF  = ws + o; o += NL*192;
  float* waF  = ws + o; o += NL*HD;
  float* baF  = ws + o; o += NL;
  float* WfF  = ws + o; o += HD;
  int*   listA= (int*)(ws + o); o += N;
  int*   listB= (int*)(ws + o); o += N;
  int*   stamp= (int*)(ws + o); o += N;        // ┐ contiguous memset region:
  int*   cnts = (int*)(ws + o); o += 16;       // │ stamp + cnts + liveB
  u8*    liveB= (u8*)(ws + o);                 // ┘ N bytes

  // cnts: [3]=init live cnt, [4..6]=touched cnts, [8]=dtype flag
  hipMemsetAsync(agg,   0, (size_t)N*HD*sizeof(float), stream);
  hipMemsetAsync(stamp, 0, (size_t)N*sizeof(int) + 16*sizeof(int) + (size_t)N, stream);
  hipMemsetAsync(d_out, 0, (size_t)N*sizeof(float), stream);

  k_dtype<<<1, 64, 0, stream>>>((const unsigned short*)rela, cnts+8);

  int prepN = 2*(NL*HD*HD) + 2*(NL*192*HD) + 2*(NL*192) + NL*HD + NL + HD + NL*NR*HD;
  k_prep<<<(prepN+255)/256, 256, 0, stream>>>(W_h, Wsp, Wih, Whh, bih, bhh, wal, bal, Wf, rela,
      WhF, WsF, WiT, WhT, biF, bhF, waF, baF, WfF, REL, cnts+8, NR);
  k_tables<<<NL*NR + NL*B, 64, 0, stream>>>(rela, Wr, Wqr, bqr, q_rel, R2, QR, cnts+8, NR, B);
  k_init<<<1, 64, 0, stream>>>(qsub, q_rel, qre, WsF, hid, HS2, liveB,
                               stamp, listA, cnts+3, cnts+8, B);

  int* curT = listB;   // touched list this layer
  int* prevL = listA;  // live list before this layer
  for (int l=0; l<NL; ++l){
    int ep = l + 2;
    k_edge<<<512, 256, 0, stream>>>(sub, rel_i, obj, eb, liveB, hid, HS2,
        R2 + (size_t)l*NR*HD, QR + (size_t)l*B*HD, REL + (size_t)l*NR*HD,
        waF + l*HD, baF + l, agg, stamp, curT, cnts+4+l, ep, E);
    k_node<<<1024, 256, 0, stream>>>(curT, cnts+4+l, agg, hid, HS2, liveB,
        WhF + (size_t)l*HD*HD, WiT + (size_t)l*192*HD, WhT + (size_t)l*192*HD,
        biF + l*192, bhF + l*192,
        (l < NL-1) ? (WsF + (size_t)(l+1)*HD*HD) : WsF,
        WfF, (float*)d_out, N, (l==0)?1:0, (l==NL-1)?1:0);
    if (l < NL-1){
      k_died<<<64, 256, 0, stream>>>(prevL, (l==0) ? (cnts+3) : (cnts+4+l-1),
                                     stamp, liveB, ep, N);
    }
    int* t = prevL; prevL = curT; curT = t;
  }
}

// Round 7
// 253.931 us; speedup vs baseline: 3.9100x; 1.0142x over previous
//
#include <hip/hip_runtime.h>
#include <hip/hip_bf16.h>

#define NL 3
#define HD 64
#define TCAP 2048
#define NB 4

typedef unsigned char u8;

__device__ __forceinline__ float sigf(float x){ return 1.f/(1.f+__expf(-x)); }

__device__ __forceinline__ float wsum(float v){
  #pragma unroll
  for (int off=32; off; off>>=1) v += __shfl_xor(v, off, 64);
  return v;
}

// broadcast lane l's value to all lanes (l compile-time constant after unroll; no LDS)
__device__ __forceinline__ float bcastf(float v, int l){
  return __int_as_float(__builtin_amdgcn_readlane(__float_as_int(v), l));
}

// dtype-flexible load: bf==1 -> bf16, bf==0 -> f32
__device__ __forceinline__ float ldin(const void* p, size_t i, int bf){
  return bf ? __bfloat162float(((const __hip_bfloat16*)p)[i]) : ((const float*)p)[i];
}

// -------- runtime dtype probe --------
__global__ void k_dtype(const unsigned short* __restrict__ probe, int* __restrict__ flag){
  int lane = threadIdx.x & 63;
  unsigned short h = probe[lane];
  int e = (h >> 7) & 0xFF;
  int sane = ((h & 0x7FFF) == 0) || (e >= 96 && e <= 132);
  unsigned long long m = __ballot(sane != 0);
  if (lane == 0) flag[0] = (__popcll(m) >= 56) ? 1 : 0;
}

// -------- convert weights to f32 scratch (input-major layouts) --------
__global__ void k_prep(
    const void* __restrict__ W_h, const void* __restrict__ Ws,
    const void* __restrict__ Wih, const void* __restrict__ Whh,
    const void* __restrict__ bih, const void* __restrict__ bhh,
    const void* __restrict__ wal, const void* __restrict__ bal,
    const void* __restrict__ Wf,  const void* __restrict__ rel,
    float* __restrict__ WhF, float* __restrict__ WsF,
    float* __restrict__ WiT, float* __restrict__ WhT,
    float* __restrict__ biF, float* __restrict__ bhF,
    float* __restrict__ waF, float* __restrict__ baF,
    float* __restrict__ WfF, float* __restrict__ REL,
    const int* __restrict__ flag, int NR)
{
  int bf = flag[0];
  int j = blockIdx.x*256 + threadIdx.x;
  const int sWT = NL*HD*HD, sWI = NL*192*HD, sB = NL*192;
  if (j < sWT){ WhF[j]=ldin(W_h,j,bf); return; } j-=sWT;
  if (j < sWT){ WsF[j]=ldin(Ws ,j,bf); return; } j-=sWT;
  if (j < sWI){ int l=j/(192*HD), q=j%(192*HD), h=q/192, a=q%192;
                WiT[j]=ldin(Wih,(size_t)l*192*HD + (size_t)a*HD + h,bf); return; } j-=sWI;
  if (j < sWI){ int l=j/(192*HD), q=j%(192*HD), h=q/192, a=q%192;
                WhT[j]=ldin(Whh,(size_t)l*192*HD + (size_t)a*HD + h,bf); return; } j-=sWI;
  if (j < sB){ biF[j]=ldin(bih,j,bf); return; } j-=sB;
  if (j < sB){ bhF[j]=ldin(bhh,j,bf); return; } j-=sB;
  if (j < NL*HD){ waF[j]=ldin(wal,j,bf); return; } j-=NL*HD;
  if (j < NL){ baF[j]=ldin(bal,j,bf); return; } j-=NL;
  if (j < HD){ WfF[j]=ldin(Wf,j,bf); return; } j-=HD;
  if (j < NL*NR*HD){ REL[j]=ldin(rel,j,bf); return; }
}

// -------- per-(layer,rel) hr@Wr and per-(layer,batch) h_qr@Wqr+bqr tables --------
__global__ void k_tables(
    const void* __restrict__ rel, const void* __restrict__ Wr,
    const void* __restrict__ Wqr, const void* __restrict__ bqr,
    const int* __restrict__ q_rel,
    float* __restrict__ R2, float* __restrict__ QR,
    const int* __restrict__ flag, int NR, int B)
{
  int bf = flag[0];
  int lane = threadIdx.x & 63;
  int bid = blockIdx.x;
  if (bid < NL*NR){
    int l = bid/NR, r = bid%NR;
    float x = ldin(rel,(size_t)(l*NR+r)*HD + lane,bf);
    float acc = 0.f;
    #pragma unroll
    for (int h=0; h<HD; ++h)
      acc = fmaf(bcastf(x, h), ldin(Wr,(size_t)(l*HD+h)*HD + lane,bf), acc);
    R2[(size_t)bid*HD + lane] = acc;
  } else {
    int b2 = bid - NL*NR;
    int l = b2/B, b = b2%B;
    int r = q_rel[b];
    float x = ldin(rel,(size_t)(l*NR+r)*HD + lane,bf);
    float acc = ldin(bqr,(size_t)l*HD + lane,bf);
    #pragma unroll
    for (int h=0; h<HD; ++h)
      acc = fmaf(bcastf(x, h), ldin(Wqr,(size_t)(l*HD+h)*HD + lane,bf), acc);
    QR[(size_t)b2*HD + lane] = acc;
  }
}

// -------- seed query nodes; build initial live list; HS2 = hid @ Ws[0] --------
__global__ void k_init(
    const int* __restrict__ qsub, const int* __restrict__ q_rel,
    const void* __restrict__ qre, const float* __restrict__ WsF0,
    float* __restrict__ hid, float* __restrict__ HS2, u8* __restrict__ liveB,
    int* __restrict__ stamp, int* __restrict__ plist, int* __restrict__ pcnt,
    const int* __restrict__ flag, int B)
{
  int bf = flag[0];
  int lane = threadIdx.x & 63;
  int pc = 0;
  for (int b=0; b<B; ++b){
    int n = qsub[b];
    int r = q_rel[b];
    float v = ldin(qre,(size_t)r*HD + lane,bf);
    hid[(size_t)n*HD + lane] = v;               // last write wins (np .at[].set)
    float acc = 0.f;
    #pragma unroll 8
    for (int h=0; h<HD; ++h)
      acc = fmaf(bcastf(v,h), WsF0[h*HD + lane], acc);
    HS2[(size_t)n*HD + lane] = acc;
    if (lane==0){
      liveB[n] = 1;
      if (stamp[n] != 1){ stamp[n] = 1; plist[pc++] = n; }
    }
  }
  if (lane==0) pcnt[0] = pc;
}

// -------- fused edge phase: scan ALL edges, process live via ballot;
//          touched-node appends buffered in LDS, one global atomic per block --------
__global__ void __launch_bounds__(256) k_edge(
    const int* __restrict__ sub, const int* __restrict__ rel_i,
    const int* __restrict__ obj, const int* __restrict__ eb,
    const u8* __restrict__ liveB,
    const float* __restrict__ hid, const float* __restrict__ HS2,
    const float* __restrict__ R2l, const float* __restrict__ QRl,
    const float* __restrict__ RELl, const float* __restrict__ waFl,
    const float* __restrict__ baFl, float* __restrict__ agg,
    int* __restrict__ stamp, int* __restrict__ tlist, int* __restrict__ tcnt,
    int ep, int E)
{
  __shared__ int s_cnt;
  __shared__ int s_base;
  __shared__ int s_buf[TCAP];
  if (threadIdx.x == 0) s_cnt = 0;
  __syncthreads();

  int lane = threadIdx.x & 63;
  int wid = (blockIdx.x*256 + threadIdx.x) >> 6;
  int nw = gridDim.x*4;
  float wa = waFl[lane];
  float ba = baFl[0];

  for (long long base = (long long)wid*64; base < E; base += (long long)nw*64){
    int e = (int)base + lane;
    int s = (e < E) ? sub[e] : 0;
    bool liv = (e < E) && (liveB[s] != 0);
    unsigned long long mask = __ballot(liv);
    while (mask){
      int bit = (int)__ffsll(mask) - 1;
      mask &= mask - 1;
      int ee = (int)base + bit;
      int ss = sub[ee], r = rel_i[ee], o = obj[ee], b = eb[ee];  // wave-uniform, L1-hot
      float hs  = hid[(size_t)ss*HD + lane];
      float pre = HS2[(size_t)ss*HD + lane] + R2l[(size_t)r*HD + lane] + QRl[(size_t)b*HD + lane];
      pre = fmaxf(pre, 0.f);
      float d = wsum(pre*wa) + ba;
      float alpha = sigf(d);
      float msg = alpha * hs * RELl[(size_t)r*HD + lane];
      unsafeAtomicAdd(&agg[(size_t)o*HD + lane], msg);
      if (lane==0){
        int old = atomicExch(&stamp[o], ep);
        if (old != ep){
          int li = atomicAdd(&s_cnt, 1);
          if (li < TCAP) s_buf[li] = o;
          else { int gi = atomicAdd(tcnt, 1); tlist[gi] = o; }  // overflow guard
        }
      }
    }
  }

  __syncthreads();
  int cnt = s_cnt; if (cnt > TCAP) cnt = TCAP;
  if (threadIdx.x == 0 && cnt > 0) s_base = atomicAdd(tcnt, cnt);
  __syncthreads();
  if (cnt > 0){
    int b0 = s_base;
    for (int i = threadIdx.x; i < cnt; i += 256) tlist[b0 + i] = s_buf[i];
  }
}

// -------- node phase: NB=4 nodes per wave -> weight bytes amortized 4x --------
__global__ void __launch_bounds__(256) k_node(
    const int* __restrict__ tlist, const int* __restrict__ tcnt,
    float* __restrict__ agg, float* __restrict__ hid, float* __restrict__ HS2,
    u8* __restrict__ liveB,
    const float* __restrict__ WhFl,  // [H][H]
    const float* __restrict__ WiTl,  // [H][3H]
    const float* __restrict__ WhTl,  // [H][3H]
    const float* __restrict__ biFl, const float* __restrict__ bhFl,
    const float* __restrict__ WsFn,  // [H][H] (next layer)
    const float* __restrict__ WfF,
    float* __restrict__ out, int N, int isFirst, int isLast)
{
  int cntv = tcnt[0]; if (cntv > N) cntv = N;
  int lane = threadIdx.x & 63;
  int wid = (blockIdx.x*256 + threadIdx.x) >> 6;
  int nw = gridDim.x*4;
  float bi0=biFl[lane], bi1=biFl[HD+lane], bi2=biFl[2*HD+lane];
  float bh0=bhFl[lane], bh1=bhFl[HD+lane], bh2=bhFl[2*HD+lane];
  float wfv = isLast ? WfF[lane] : 0.f;

  for (int i0 = wid*NB; i0 < cntv; i0 += nw*NB){
    int nd[NB]; bool val[NB]; float av[NB];
    #pragma unroll
    for (int j=0;j<NB;++j){
      val[j] = (i0+j) < cntv;
      nd[j]  = tlist[val[j] ? (i0+j) : i0];
      av[j]  = val[j] ? agg[(size_t)nd[j]*HD + lane] : 0.f;
    }
    if (!isLast){
      #pragma unroll
      for (int j=0;j<NB;++j) if (val[j]) agg[(size_t)nd[j]*HD + lane] = 0.f;
    }

    // hm = relu(av @ W_h): one weight load feeds NB FMAs
    float hm[NB] = {0.f,0.f,0.f,0.f};
    #pragma unroll 8
    for (int h=0; h<HD; ++h){
      float w = WhFl[h*HD + lane];
      #pragma unroll
      for (int j=0;j<NB;++j) hm[j] = fmaf(bcastf(av[j],h), w, hm[j]);
    }
    float mask[NB]; float h0v[NB];
    #pragma unroll
    for (int j=0;j<NB;++j){
      hm[j] = fmaxf(hm[j], 0.f);
      mask[j] = (__ballot(hm[j] != 0.f) != 0ull) ? 1.f : 0.f;
      h0v[j] = 0.f;
    }
    if (!isFirst){
      #pragma unroll
      for (int j=0;j<NB;++j){
        bool wl = val[j] && (liveB[nd[j]] != 0);
        float hv = hid[(size_t)nd[j]*HD + lane];   // unconditional load, selected
        h0v[j] = wl ? hv : 0.f;
      }
    }

    float gi0[NB], gi1[NB], gi2[NB], gh0[NB], gh1[NB], gh2[NB];
    #pragma unroll
    for (int j=0;j<NB;++j){ gi0[j]=bi0; gi1[j]=bi1; gi2[j]=bi2; gh0[j]=bh0; gh1[j]=bh1; gh2[j]=bh2; }
    #pragma unroll 4
    for (int h=0; h<HD; ++h){
      const float* __restrict__ wr = WiTl + (size_t)h*192;
      float w0 = wr[lane], w1 = wr[64+lane], w2 = wr[128+lane];
      #pragma unroll
      for (int j=0;j<NB;++j){
        float x = bcastf(hm[j],h);
        gi0[j] = fmaf(x, w0, gi0[j]);
        gi1[j] = fmaf(x, w1, gi1[j]);
        gi2[j] = fmaf(x, w2, gi2[j]);
      }
    }
    if (!isFirst){
      #pragma unroll 4
      for (int h=0; h<HD; ++h){
        const float* __restrict__ wr = WhTl + (size_t)h*192;
        float w0 = wr[lane], w1 = wr[64+lane], w2 = wr[128+lane];
        #pragma unroll
        for (int j=0;j<NB;++j){
          float y = bcastf(h0v[j],h);
          gh0[j] = fmaf(y, w0, gh0[j]);
          gh1[j] = fmaf(y, w1, gh1[j]);
          gh2[j] = fmaf(y, w2, gh2[j]);
        }
      }
    }

    float hn[NB];
    #pragma unroll
    for (int j=0;j<NB;++j){
      float r = sigf(gi0[j]+gh0[j]);
      float z = sigf(gi1[j]+gh1[j]);
      float nn = tanhf(gi2[j] + r*gh2[j]);
      hn[j] = ((1.f - z)*nn + z*h0v[j])*mask[j];
    }

    if (isLast){
      #pragma unroll
      for (int j=0;j<NB;++j){
        float sc = wsum(hn[j] * wfv);
        if (lane==0 && val[j]) out[nd[j]] = sc;
      }
      continue;
    }
    #pragma unroll
    for (int j=0;j<NB;++j){
      unsigned long long lv = __ballot(hn[j] != 0.f);
      if (val[j]){
        hid[(size_t)nd[j]*HD + lane] = hn[j];
        if (lane==0) liveB[nd[j]] = lv ? (u8)1 : (u8)0;
      }
    }

    // HS2 for next layer: hn @ Ws[l+1]
    float acc[NB] = {0.f,0.f,0.f,0.f};
    #pragma unroll 8
    for (int h=0; h<HD; ++h){
      float w = WsFn[h*HD + lane];
      #pragma unroll
      for (int j=0;j<NB;++j) acc[j] = fmaf(bcastf(hn[j],h), w, acc[j]);
    }
    #pragma unroll
    for (int j=0;j<NB;++j) if (val[j]) HS2[(size_t)nd[j]*HD + lane] = acc[j];
  }
}

// -------- clear liveness of prev-live nodes that received no messages --------
__global__ void k_died(const int* __restrict__ plist, const int* __restrict__ pcnt,
                       const int* __restrict__ stamp, u8* __restrict__ liveB, int ep, int N)
{
  int cntv = pcnt[0]; if (cntv > N) cntv = N;
  int t = blockIdx.x*256 + threadIdx.x;
  for (int i = t; i < cntv; i += gridDim.x*256){
    int n = plist[i];
    if (stamp[n] != ep) liveB[n] = 0;
  }
}

extern "C" void kernel_launch(void* const* d_in, const int* in_sizes, int n_in,
                              void* d_out, int out_size, void* d_ws, size_t ws_size,
                              hipStream_t stream)
{
  const int* sub   = (const int*)d_in[0];
  const int* rel_i = (const int*)d_in[1];
  const int* obj   = (const int*)d_in[2];
  const int* eb    = (const int*)d_in[3];
  const int* q_rel = (const int*)d_in[4];
  const int* qsub  = (const int*)d_in[5];
  const void* rela = d_in[6];
  const void* qre  = d_in[7];
  const void* Wsp  = d_in[8];
  const void* Wr   = d_in[9];
  const void* Wqr  = d_in[10];
  const void* bqr  = d_in[11];
  const void* wal  = d_in[12];
  const void* bal  = d_in[13];
  const void* W_h  = d_in[14];
  const void* Wih  = d_in[15];
  const void* Whh  = d_in[16];
  const void* bih  = d_in[17];
  const void* bhh  = d_in[18];
  const void* Wf   = d_in[19];

  int E  = in_sizes[0];
  int B  = in_sizes[4];
  int NR = in_sizes[6]/(NL*HD);
  int N  = out_size;

  float* ws = (float*)d_ws;
  size_t o = 0;
  float* agg  = ws + o; o += (size_t)N*HD;     // memset to 0 each call
  float* hid  = ws + o; o += (size_t)N*HD;     // no memset (reads guarded by liveB)
  float* HS2  = ws + o; o += (size_t)N*HD;     // no memset (reads only for live subs)
  float* R2   = ws + o; o += (size_t)NL*NR*HD;
  float* QR   = ws + o; o += (size_t)NL*B*HD;
  float* REL  = ws + o; o += (size_t)NL*NR*HD;
  float* WhF  = ws + o; o += NL*HD*HD;
  float* WsF  = ws + o; o += NL*HD*HD;
  float* WiT  = ws + o; o += NL*192*HD;
  float* WhT  = ws + o; o += NL*192*HD;
  float* biF  = ws + o; o += NL*192;
  float* bhF  = ws + o; o += NL*192;
  float* waF  = ws + o; o += NL*HD;
  float* baF  = ws + o; o += NL;
  float* WfF  = ws + o; o += HD;
  int*   listA= (int*)(ws + o); o += N;
  int*   listB= (int*)(ws + o); o += N;
  int*   stamp= (int*)(ws + o); o += N;        // ┐ contiguous memset region:
  int*   cnts = (int*)(ws + o); o += 16;       // │ stamp + cnts + liveB
  u8*    liveB= (u8*)(ws + o);                 // ┘ N bytes

  // cnts: [3]=init live cnt, [4..6]=touched cnts, [8]=dtype flag
  hipMemsetAsync(agg,   0, (size_t)N*HD*sizeof(float), stream);
  hipMemsetAsync(stamp, 0, (size_t)N*sizeof(int) + 16*sizeof(int) + (size_t)N, stream);
  hipMemsetAsync(d_out, 0, (size_t)N*sizeof(float), stream);

  k_dtype<<<1, 64, 0, stream>>>((const unsigned short*)rela, cnts+8);

  int prepN = 2*(NL*HD*HD) + 2*(NL*192*HD) + 2*(NL*192) + NL*HD + NL + HD + NL*NR*HD;
  k_prep<<<(prepN+255)/256, 256, 0, stream>>>(W_h, Wsp, Wih, Whh, bih, bhh, wal, bal, Wf, rela,
      WhF, WsF, WiT, WhT, biF, bhF, waF, baF, WfF, REL, cnts+8, NR);
  k_tables<<<NL*NR + NL*B, 64, 0, stream>>>(rela, Wr, Wqr, bqr, q_rel, R2, QR, cnts+8, NR, B);
  k_init<<<1, 64, 0, stream>>>(qsub, q_rel, qre, WsF, hid, HS2, liveB,
                               stamp, listA, cnts+3, cnts+8, B);

  int* curT = listB;   // touched list this layer
  int* prevL = listA;  // live list before this layer
  for (int l=0; l<NL; ++l){
    int ep = l + 2;
    k_edge<<<1024, 256, 0, stream>>>(sub, rel_i, obj, eb, liveB, hid, HS2,
        R2 + (size_t)l*NR*HD, QR + (size_t)l*B*HD, REL + (size_t)l*NR*HD,
        waF + l*HD, baF + l, agg, stamp, curT, cnts+4+l, ep, E);
    k_node<<<2048, 256, 0, stream>>>(curT, cnts+4+l, agg, hid, HS2, liveB,
        WhF + (size_t)l*HD*HD, WiT + (size_t)l*192*HD, WhT + (size_t)l*192*HD,
        biF + l*192, bhF + l*192,
        (l < NL-1) ? (WsF + (size_t)(l+1)*HD*HD) : WsF,
        WfF, (float*)d_out, N, (l==0)?1:0, (l==NL-1)?1:0);
    if (l < NL-1){
      k_died<<<64, 256, 0, stream>>>(prevL, (l==0) ? (cnts+3) : (cnts+4+l-1),
                                     stamp, liveB, ep, N);
    }
    int* t = prevL; prevL = curT; curT = t;
  }
}

// Round 8
// 197.424 us; speedup vs baseline: 5.0291x; 1.2862x over previous
//
#include <hip/hip_runtime.h>
#include <hip/hip_bf16.h>

#define NL 3
#define HD 64
#define TCAP 2048
#define NB 4

typedef unsigned char u8;

__device__ __forceinline__ float sigf(float x){ return 1.f/(1.f+__expf(-x)); }

__device__ __forceinline__ float wsum(float v){
  #pragma unroll
  for (int off=32; off; off>>=1) v += __shfl_xor(v, off, 64);
  return v;
}

// broadcast lane l's value to all lanes (l compile-time constant after unroll; no LDS)
__device__ __forceinline__ float bcastf(float v, int l){
  return __int_as_float(__builtin_amdgcn_readlane(__float_as_int(v), l));
}

// dtype-flexible load: bf==1 -> bf16, bf==0 -> f32
__device__ __forceinline__ float ldin(const void* p, size_t i, int bf){
  return bf ? __bfloat162float(((const __hip_bfloat16*)p)[i]) : ((const float*)p)[i];
}

// -------- runtime dtype probe --------
__global__ void k_dtype(const unsigned short* __restrict__ probe, int* __restrict__ flag){
  int lane = threadIdx.x & 63;
  unsigned short h = probe[lane];
  int e = (h >> 7) & 0xFF;
  int sane = ((h & 0x7FFF) == 0) || (e >= 96 && e <= 132);
  unsigned long long m = __ballot(sane != 0);
  if (lane == 0) flag[0] = (__popcll(m) >= 56) ? 1 : 0;
}

// -------- convert weights to f32 scratch (input-major layouts) --------
__global__ void k_prep(
    const void* __restrict__ W_h, const void* __restrict__ Ws,
    const void* __restrict__ Wih, const void* __restrict__ Whh,
    const void* __restrict__ bih, const void* __restrict__ bhh,
    const void* __restrict__ wal, const void* __restrict__ bal,
    const void* __restrict__ Wf,  const void* __restrict__ rel,
    float* __restrict__ WhF, float* __restrict__ WsF,
    float* __restrict__ WiT, float* __restrict__ WhT,
    float* __restrict__ biF, float* __restrict__ bhF,
    float* __restrict__ waF, float* __restrict__ baF,
    float* __restrict__ WfF, float* __restrict__ REL,
    const int* __restrict__ flag, int NR)
{
  int bf = flag[0];
  int j = blockIdx.x*256 + threadIdx.x;
  const int sWT = NL*HD*HD, sWI = NL*192*HD, sB = NL*192;
  if (j < sWT){ WhF[j]=ldin(W_h,j,bf); return; } j-=sWT;
  if (j < sWT){ WsF[j]=ldin(Ws ,j,bf); return; } j-=sWT;
  if (j < sWI){ int l=j/(192*HD), q=j%(192*HD), h=q/192, a=q%192;
                WiT[j]=ldin(Wih,(size_t)l*192*HD + (size_t)a*HD + h,bf); return; } j-=sWI;
  if (j < sWI){ int l=j/(192*HD), q=j%(192*HD), h=q/192, a=q%192;
                WhT[j]=ldin(Whh,(size_t)l*192*HD + (size_t)a*HD + h,bf); return; } j-=sWI;
  if (j < sB){ biF[j]=ldin(bih,j,bf); return; } j-=sB;
  if (j < sB){ bhF[j]=ldin(bhh,j,bf); return; } j-=sB;
  if (j < NL*HD){ waF[j]=ldin(wal,j,bf); return; } j-=NL*HD;
  if (j < NL){ baF[j]=ldin(bal,j,bf); return; } j-=NL;
  if (j < HD){ WfF[j]=ldin(Wf,j,bf); return; } j-=HD;
  if (j < NL*NR*HD){ REL[j]=ldin(rel,j,bf); return; }
}

// -------- per-(layer,rel) hr@Wr and per-(layer,batch) h_qr@Wqr+bqr tables --------
__global__ void k_tables(
    const void* __restrict__ rel, const void* __restrict__ Wr,
    const void* __restrict__ Wqr, const void* __restrict__ bqr,
    const int* __restrict__ q_rel,
    float* __restrict__ R2, float* __restrict__ QR,
    const int* __restrict__ flag, int NR, int B)
{
  int bf = flag[0];
  int lane = threadIdx.x & 63;
  int bid = blockIdx.x;
  if (bid < NL*NR){
    int l = bid/NR, r = bid%NR;
    float x = ldin(rel,(size_t)(l*NR+r)*HD + lane,bf);
    float acc = 0.f;
    #pragma unroll
    for (int h=0; h<HD; ++h)
      acc = fmaf(bcastf(x, h), ldin(Wr,(size_t)(l*HD+h)*HD + lane,bf), acc);
    R2[(size_t)bid*HD + lane] = acc;
  } else {
    int b2 = bid - NL*NR;
    int l = b2/B, b = b2%B;
    int r = q_rel[b];
    float x = ldin(rel,(size_t)(l*NR+r)*HD + lane,bf);
    float acc = ldin(bqr,(size_t)l*HD + lane,bf);
    #pragma unroll
    for (int h=0; h<HD; ++h)
      acc = fmaf(bcastf(x, h), ldin(Wqr,(size_t)(l*HD+h)*HD + lane,bf), acc);
    QR[(size_t)b2*HD + lane] = acc;
  }
}

// -------- seed query nodes IN PARALLEL (one block per b; last-writer-wins dedupe) --------
__global__ void k_init(
    const int* __restrict__ qsub, const int* __restrict__ q_rel,
    const void* __restrict__ qre, const float* __restrict__ WsF0,
    float* __restrict__ hid, float* __restrict__ HS2, u8* __restrict__ liveB,
    int* __restrict__ stamp, int* __restrict__ plist, int* __restrict__ pcnt,
    const int* __restrict__ flag, int B)
{
  int bf = flag[0];
  int lane = threadIdx.x & 63;
  int b = blockIdx.x;
  int n = qsub[b];
  // np .at[].set with sequential writes: LAST duplicate wins -> skip if a later b' hits n
  for (int b2 = b+1; b2 < B; ++b2) if (qsub[b2] == n) return;
  int r = q_rel[b];
  float v = ldin(qre,(size_t)r*HD + lane,bf);
  hid[(size_t)n*HD + lane] = v;
  float acc = 0.f;
  #pragma unroll 8
  for (int h=0; h<HD; ++h)
    acc = fmaf(bcastf(v,h), WsF0[h*HD + lane], acc);
  HS2[(size_t)n*HD + lane] = acc;
  if (lane==0){
    liveB[n] = 1;
    stamp[n] = 1;                       // != any layer epoch (2..4)
    int idx = atomicAdd(pcnt, 1);       // unordered set; consumed only by k_died
    plist[idx] = n;
  }
}

// -------- fused edge phase: scan ALL edges, process live via ballot;
//          touched-node appends buffered in LDS, one global atomic per block --------
__global__ void __launch_bounds__(256) k_edge(
    const int* __restrict__ sub, const int* __restrict__ rel_i,
    const int* __restrict__ obj, const int* __restrict__ eb,
    const u8* __restrict__ liveB,
    const float* __restrict__ hid, const float* __restrict__ HS2,
    const float* __restrict__ R2l, const float* __restrict__ QRl,
    const float* __restrict__ RELl, const float* __restrict__ waFl,
    const float* __restrict__ baFl, float* __restrict__ agg,
    int* __restrict__ stamp, int* __restrict__ tlist, int* __restrict__ tcnt,
    int ep, int E)
{
  __shared__ int s_cnt;
  __shared__ int s_base;
  __shared__ int s_buf[TCAP];
  if (threadIdx.x == 0) s_cnt = 0;
  __syncthreads();

  int lane = threadIdx.x & 63;
  int wid = (blockIdx.x*256 + threadIdx.x) >> 6;
  int nw = gridDim.x*4;
  float wa = waFl[lane];
  float ba = baFl[0];

  for (long long base = (long long)wid*64; base < E; base += (long long)nw*64){
    int e = (int)base + lane;
    int s = (e < E) ? sub[e] : 0;
    bool liv = (e < E) && (liveB[s] != 0);
    unsigned long long mask = __ballot(liv);
    while (mask){
      int bit = (int)__ffsll(mask) - 1;
      mask &= mask - 1;
      int ee = (int)base + bit;
      int ss = sub[ee], r = rel_i[ee], o = obj[ee], b = eb[ee];  // wave-uniform, L1-hot
      float hs  = hid[(size_t)ss*HD + lane];
      float pre = HS2[(size_t)ss*HD + lane] + R2l[(size_t)r*HD + lane] + QRl[(size_t)b*HD + lane];
      pre = fmaxf(pre, 0.f);
      float d = wsum(pre*wa) + ba;
      float alpha = sigf(d);
      float msg = alpha * hs * RELl[(size_t)r*HD + lane];
      unsafeAtomicAdd(&agg[(size_t)o*HD + lane], msg);
      if (lane==0){
        int old = atomicExch(&stamp[o], ep);
        if (old != ep){
          int li = atomicAdd(&s_cnt, 1);
          if (li < TCAP) s_buf[li] = o;
          else { int gi = atomicAdd(tcnt, 1); tlist[gi] = o; }  // overflow guard
        }
      }
    }
  }

  __syncthreads();
  int cnt = s_cnt; if (cnt > TCAP) cnt = TCAP;
  if (threadIdx.x == 0 && cnt > 0) s_base = atomicAdd(tcnt, cnt);
  __syncthreads();
  if (cnt > 0){
    int b0 = s_base;
    for (int i = threadIdx.x; i < cnt; i += 256) tlist[b0 + i] = s_buf[i];
  }
}

// -------- node phase: NB=4 nodes per wave -> weight bytes amortized 4x --------
__global__ void __launch_bounds__(256) k_node(
    const int* __restrict__ tlist, const int* __restrict__ tcnt,
    float* __restrict__ agg, float* __restrict__ hid, float* __restrict__ HS2,
    u8* __restrict__ liveB,
    const float* __restrict__ WhFl,  // [H][H]
    const float* __restrict__ WiTl,  // [H][3H]
    const float* __restrict__ WhTl,  // [H][3H]
    const float* __restrict__ biFl, const float* __restrict__ bhFl,
    const float* __restrict__ WsFn,  // [H][H] (next layer)
    const float* __restrict__ WfF,
    float* __restrict__ out, int N, int isFirst, int isLast)
{
  int cntv = tcnt[0]; if (cntv > N) cntv = N;
  int lane = threadIdx.x & 63;
  int wid = (blockIdx.x*256 + threadIdx.x) >> 6;
  int nw = gridDim.x*4;
  float bi0=biFl[lane], bi1=biFl[HD+lane], bi2=biFl[2*HD+lane];
  float bh0=bhFl[lane], bh1=bhFl[HD+lane], bh2=bhFl[2*HD+lane];
  float wfv = isLast ? WfF[lane] : 0.f;

  for (int i0 = wid*NB; i0 < cntv; i0 += nw*NB){
    int nd[NB]; bool val[NB]; float av[NB];
    #pragma unroll
    for (int j=0;j<NB;++j){
      val[j] = (i0+j) < cntv;
      nd[j]  = tlist[val[j] ? (i0+j) : i0];
      av[j]  = val[j] ? agg[(size_t)nd[j]*HD + lane] : 0.f;
    }
    if (!isLast){
      #pragma unroll
      for (int j=0;j<NB;++j) if (val[j]) agg[(size_t)nd[j]*HD + lane] = 0.f;
    }

    // hm = relu(av @ W_h): one weight load feeds NB FMAs
    float hm[NB] = {0.f,0.f,0.f,0.f};
    #pragma unroll 8
    for (int h=0; h<HD; ++h){
      float w = WhFl[h*HD + lane];
      #pragma unroll
      for (int j=0;j<NB;++j) hm[j] = fmaf(bcastf(av[j],h), w, hm[j]);
    }
    float mask[NB]; float h0v[NB];
    #pragma unroll
    for (int j=0;j<NB;++j){
      hm[j] = fmaxf(hm[j], 0.f);
      mask[j] = (__ballot(hm[j] != 0.f) != 0ull) ? 1.f : 0.f;
      h0v[j] = 0.f;
    }
    if (!isFirst){
      #pragma unroll
      for (int j=0;j<NB;++j){
        bool wl = val[j] && (liveB[nd[j]] != 0);
        float hv = hid[(size_t)nd[j]*HD + lane];   // unconditional load, selected
        h0v[j] = wl ? hv : 0.f;
      }
    }

    float gi0[NB], gi1[NB], gi2[NB], gh0[NB], gh1[NB], gh2[NB];
    #pragma unroll
    for (int j=0;j<NB;++j){ gi0[j]=bi0; gi1[j]=bi1; gi2[j]=bi2; gh0[j]=bh0; gh1[j]=bh1; gh2[j]=bh2; }
    #pragma unroll 4
    for (int h=0; h<HD; ++h){
      const float* __restrict__ wr = WiTl + (size_t)h*192;
      float w0 = wr[lane], w1 = wr[64+lane], w2 = wr[128+lane];
      #pragma unroll
      for (int j=0;j<NB;++j){
        float x = bcastf(hm[j],h);
        gi0[j] = fmaf(x, w0, gi0[j]);
        gi1[j] = fmaf(x, w1, gi1[j]);
        gi2[j] = fmaf(x, w2, gi2[j]);
      }
    }
    if (!isFirst){
      #pragma unroll 4
      for (int h=0; h<HD; ++h){
        const float* __restrict__ wr = WhTl + (size_t)h*192;
        float w0 = wr[lane], w1 = wr[64+lane], w2 = wr[128+lane];
        #pragma unroll
        for (int j=0;j<NB;++j){
          float y = bcastf(h0v[j],h);
          gh0[j] = fmaf(y, w0, gh0[j]);
          gh1[j] = fmaf(y, w1, gh1[j]);
          gh2[j] = fmaf(y, w2, gh2[j]);
        }
      }
    }

    float hn[NB];
    #pragma unroll
    for (int j=0;j<NB;++j){
      float r = sigf(gi0[j]+gh0[j]);
      float z = sigf(gi1[j]+gh1[j]);
      float nn = tanhf(gi2[j] + r*gh2[j]);
      hn[j] = ((1.f - z)*nn + z*h0v[j])*mask[j];
    }

    if (isLast){
      #pragma unroll
      for (int j=0;j<NB;++j){
        float sc = wsum(hn[j] * wfv);
        if (lane==0 && val[j]) out[nd[j]] = sc;
      }
      continue;
    }
    #pragma unroll
    for (int j=0;j<NB;++j){
      unsigned long long lv = __ballot(hn[j] != 0.f);
      if (val[j]){
        hid[(size_t)nd[j]*HD + lane] = hn[j];
        if (lane==0) liveB[nd[j]] = lv ? (u8)1 : (u8)0;
      }
    }

    // HS2 for next layer: hn @ Ws[l+1]
    float acc[NB] = {0.f,0.f,0.f,0.f};
    #pragma unroll 8
    for (int h=0; h<HD; ++h){
      float w = WsFn[h*HD + lane];
      #pragma unroll
      for (int j=0;j<NB;++j) acc[j] = fmaf(bcastf(hn[j],h), w, acc[j]);
    }
    #pragma unroll
    for (int j=0;j<NB;++j) if (val[j]) HS2[(size_t)nd[j]*HD + lane] = acc[j];
  }
}

// -------- clear liveness of prev-live nodes that received no messages --------
__global__ void k_died(const int* __restrict__ plist, const int* __restrict__ pcnt,
                       const int* __restrict__ stamp, u8* __restrict__ liveB, int ep, int N)
{
  int cntv = pcnt[0]; if (cntv > N) cntv = N;
  int t = blockIdx.x*256 + threadIdx.x;
  for (int i = t; i < cntv; i += gridDim.x*256){
    int n = plist[i];
    if (stamp[n] != ep) liveB[n] = 0;
  }
}

extern "C" void kernel_launch(void* const* d_in, const int* in_sizes, int n_in,
                              void* d_out, int out_size, void* d_ws, size_t ws_size,
                              hipStream_t stream)
{
  const int* sub   = (const int*)d_in[0];
  const int* rel_i = (const int*)d_in[1];
  const int* obj   = (const int*)d_in[2];
  const int* eb    = (const int*)d_in[3];
  const int* q_rel = (const int*)d_in[4];
  const int* qsub  = (const int*)d_in[5];
  const void* rela = d_in[6];
  const void* qre  = d_in[7];
  const void* Wsp  = d_in[8];
  const void* Wr   = d_in[9];
  const void* Wqr  = d_in[10];
  const void* bqr  = d_in[11];
  const void* wal  = d_in[12];
  const void* bal  = d_in[13];
  const void* W_h  = d_in[14];
  const void* Wih  = d_in[15];
  const void* Whh  = d_in[16];
  const void* bih  = d_in[17];
  const void* bhh  = d_in[18];
  const void* Wf   = d_in[19];

  int E  = in_sizes[0];
  int B  = in_sizes[4];
  int NR = in_sizes[6]/(NL*HD);
  int N  = out_size;

  float* ws = (float*)d_ws;
  size_t o = 0;
  float* agg  = ws + o; o += (size_t)N*HD;     // memset to 0 each call
  float* hid  = ws + o; o += (size_t)N*HD;     // no memset (reads guarded by liveB)
  float* HS2  = ws + o; o += (size_t)N*HD;     // no memset (reads only for live subs)
  float* R2   = ws + o; o += (size_t)NL*NR*HD;
  float* QR   = ws + o; o += (size_t)NL*B*HD;
  float* REL  = ws + o; o += (size_t)NL*NR*HD;
  float* WhF  = ws + o; o += NL*HD*HD;
  float* WsF  = ws + o; o += NL*HD*HD;
  float* WiT  = ws + o; o += NL*192*HD;
  float* WhT  = ws + o; o += NL*192*HD;
  float* biF  = ws + o; o += NL*192;
  float* bhF  = ws + o; o += NL*192;
  float* waF  = ws + o; o += NL*HD;
  float* baF  = ws + o; o += NL;
  float* WfF  = ws + o; o += HD;
  int*   listA= (int*)(ws + o); o += N;
  int*   listB= (int*)(ws + o); o += N;
  int*   stamp= (int*)(ws + o); o += N;        // ┐ contiguous memset region:
  int*   cnts = (int*)(ws + o); o += 16;       // │ stamp + cnts + liveB
  u8*    liveB= (u8*)(ws + o);                 // ┘ N bytes

  // cnts: [3]=init live cnt, [4..6]=touched cnts, [8]=dtype flag
  hipMemsetAsync(agg,   0, (size_t)N*HD*sizeof(float), stream);
  hipMemsetAsync(stamp, 0, (size_t)N*sizeof(int) + 16*sizeof(int) + (size_t)N, stream);
  hipMemsetAsync(d_out, 0, (size_t)N*sizeof(float), stream);

  k_dtype<<<1, 64, 0, stream>>>((const unsigned short*)rela, cnts+8);

  int prepN = 2*(NL*HD*HD) + 2*(NL*192*HD) + 2*(NL*192) + NL*HD + NL + HD + NL*NR*HD;
  k_prep<<<(prepN+255)/256, 256, 0, stream>>>(W_h, Wsp, Wih, Whh, bih, bhh, wal, bal, Wf, rela,
      WhF, WsF, WiT, WhT, biF, bhF, waF, baF, WfF, REL, cnts+8, NR);
  k_tables<<<NL*NR + NL*B, 64, 0, stream>>>(rela, Wr, Wqr, bqr, q_rel, R2, QR, cnts+8, NR, B);
  k_init<<<B, 64, 0, stream>>>(qsub, q_rel, qre, WsF, hid, HS2, liveB,
                               stamp, listA, cnts+3, cnts+8, B);

  int* curT = listB;   // touched list this layer
  int* prevL = listA;  // live list before this layer
  for (int l=0; l<NL; ++l){
    int ep = l + 2;
    k_edge<<<1024, 256, 0, stream>>>(sub, rel_i, obj, eb, liveB, hid, HS2,
        R2 + (size_t)l*NR*HD, QR + (size_t)l*B*HD, REL + (size_t)l*NR*HD,
        waF + l*HD, baF + l, agg, stamp, curT, cnts+4+l, ep, E);
    k_node<<<2048, 256, 0, stream>>>(curT, cnts+4+l, agg, hid, HS2, liveB,
        WhF + (size_t)l*HD*HD, WiT + (size_t)l*192*HD, WhT + (size_t)l*192*HD,
        biF + l*192, bhF + l*192,
        (l < NL-1) ? (WsF + (size_t)(l+1)*HD*HD) : WsF,
        WfF, (float*)d_out, N, (l==0)?1:0, (l==NL-1)?1:0);
    if (l < NL-1){
      k_died<<<64, 256, 0, stream>>>(prevL, (l==0) ? (cnts+3) : (cnts+4+l-1),
                                     stamp, liveB, ep, N);
    }
    int* t = prevL; prevL = curT; curT = t;
  }
}